// Round 16
// baseline (265.962 us; speedup 1.0000x reference)
//
#include <hip/hip_runtime.h>
#include <cstddef>
#include <cstdint>

constexpr int LSEQ = 4096;
constexpr int DM   = 1024;
constexpr int HD   = 64;
constexpr int BHT  = 32;     // B*H
constexpr int TOPU = 819;
constexpr int MROWS = 8192;  // B*L
constexpr int NSEG = 4;      // attention split-K segments
constexpr int UCAP = 1024;   // uncertain-row capacity per bh
#define BAND 2.4e-3f         // 6-sigma bound on approx-norm relative error
#define QSCALE 0.180336880f  // 0.125 * log2(e): softmax scale in log2 domain

typedef unsigned short u16;
typedef unsigned long long u64;
typedef __attribute__((ext_vector_type(8))) short short8v;  // 8 bf16
typedef __attribute__((ext_vector_type(4))) short short4v;  // 4 bf16
typedef __attribute__((ext_vector_type(4))) float f32x4;

__device__ __forceinline__ u16 f2bf(float f) {
  uint32_t u = __float_as_uint(f);
  u += 0x7fffu + ((u >> 16) & 1u);   // RNE
  return (u16)(u >> 16);
}
__device__ __forceinline__ float bf2f(u16 h) {
  return __uint_as_float(((uint32_t)h) << 16);
}
// native 2^x (v_exp_f32 IS exp2)
__device__ __forceinline__ float fexp2(float x) {
  float r; asm("v_exp_f32 %0, %1" : "=v"(r) : "v"(x)); return r;
}

// async 16B global -> LDS (DMA).  LDS dest wave-uniform base; HW adds lane*16.
__device__ __forceinline__ void gl16(const void* g, void* l) {
  __builtin_amdgcn_global_load_lds(
      (const __attribute__((address_space(1))) void*)g,
      (__attribute__((address_space(3))) void*)l, 16, 0, 0);
}

// Inverse of the LDS swizzle e = (R*32 + C*8) ^ ((R&7)<<3) for linear slot S.
__device__ __forceinline__ void inv_swz(int S, int& R, int& C) {
  const int R0 = ((S >> 5) ^ (S >> 7)) & 1;
  const int R1 = (S >> 6) & 1;
  R = ((S >> 6) << 1) | R0;
  C = (((S >> 3) & 1) ^ R0) | ((((S >> 4) & 1) ^ R1) << 1);
}

// ---------------------------------------------------------------------------
// Prep: bf16 conversions only (x, Wq, Wk, Wv, Wo).  O1b memset kept SEPARATE
// and late: fusing it here pollutes L2 right before gemm_proj (round-15
// lesson: +8 MB FETCH, +12 us on proj).
// ---------------------------------------------------------------------------
__device__ __forceinline__ void conv_body(const float* src, u16* dst, int i) {
  const float4 a = *reinterpret_cast<const float4*>(src + (size_t)i * 8);
  const float4 b = *reinterpret_cast<const float4*>(src + (size_t)i * 8 + 4);
  short8v v;
  v[0] = (short)f2bf(a.x); v[1] = (short)f2bf(a.y);
  v[2] = (short)f2bf(a.z); v[3] = (short)f2bf(a.w);
  v[4] = (short)f2bf(b.x); v[5] = (short)f2bf(b.y);
  v[6] = (short)f2bf(b.z); v[7] = (short)f2bf(b.w);
  *reinterpret_cast<short8v*>(dst + (size_t)i * 8) = v;
}

__global__ __launch_bounds__(256) void prep_all(
    const float* __restrict__ x,  const float* __restrict__ Wq,
    const float* __restrict__ Wk, const float* __restrict__ Wv,
    const float* __restrict__ Wo,
    u16* __restrict__ xb, u16* __restrict__ Wqb, u16* __restrict__ Wkb,
    u16* __restrict__ Wvb, u16* __restrict__ Wob)
{
  const int NX = MROWS * DM / 8;   // 1048576
  const int NW = DM * DM / 8;      // 131072
  int i = blockIdx.x * 256 + threadIdx.x;
  if (i < NX)  { conv_body(x,  xb,  i); return; }
  i -= NX;
  if (i < NW)  { conv_body(Wq, Wqb, i); return; }
  i -= NW;
  if (i < NW)  { conv_body(Wk, Wkb, i); return; }
  i -= NW;
  if (i < NW)  { conv_body(Wv, Wvb, i); return; }
  i -= NW;
  if (i < NW)  { conv_body(Wo, Wob, i); }
}

// ---------------------------------------------------------------------------
// Single-product projection body, split-head bf16 out (scaled by oscale);
// optional fused norms on the UNSCALED values (Q mode).
// ---------------------------------------------------------------------------
__device__ __forceinline__ void proj_sh_body(
    u16* smem, const u16* __restrict__ Xb, const u16* __restrict__ Wb,
    const float* __restrict__ bias, u16* __restrict__ dst,
    float* __restrict__ norms, float oscale, int bx, int ny)
{
  u16* As = smem;
  u16* Bs = smem + 4096;
  const int tid = threadIdx.x;
  const int m0 = bx * 128, n0 = ny * 128;
  const int wid = tid >> 6, lane = tid & 63;
  const int wr = (wid >> 1) * 64, wc = (wid & 1) * 64;
  const int c = lane & 15, G = lane >> 4;

  int Rr[2], Cr[2];
  #pragma unroll
  for (int rr = 0; rr < 2; ++rr) inv_swz((tid + rr * 256) * 8, Rr[rr], Cr[rr]);

  f32x4 acc[4][4];
  #pragma unroll
  for (int mt = 0; mt < 4; ++mt)
    #pragma unroll
    for (int nt = 0; nt < 4; ++nt)
      acc[mt][nt] = (f32x4){0.f, 0.f, 0.f, 0.f};

  for (int k0 = 0; k0 < DM; k0 += 32) {
    #pragma unroll
    for (int rr = 0; rr < 2; ++rr) {
      const size_t goA = (size_t)(m0 + Rr[rr]) * DM + k0 + Cr[rr] * 8;
      const size_t goB = (size_t)(n0 + Rr[rr]) * DM + k0 + Cr[rr] * 8;
      const int lb = wid * 512 + rr * 2048;
      gl16(Xb + goA, As + lb);
      gl16(Wb + goB, Bs + lb);
    }
    __syncthreads();

    short8v af[4], bf[4];
    #pragma unroll
    for (int mt = 0; mt < 4; ++mt) {
      const int m = wr + mt * 16 + c;
      af[mt] = *reinterpret_cast<const short8v*>(As + ((m * 32 + G * 8) ^ ((m & 7) << 3)));
      const int n = wc + mt * 16 + c;
      bf[mt] = *reinterpret_cast<const short8v*>(Bs + ((n * 32 + G * 8) ^ ((n & 7) << 3)));
    }
    #pragma unroll
    for (int mt = 0; mt < 4; ++mt)
      #pragma unroll
      for (int nt = 0; nt < 4; ++nt)
        acc[mt][nt] = __builtin_amdgcn_mfma_f32_16x16x32_bf16(af[mt], bf[nt], acc[mt][nt], 0, 0, 0);
    __syncthreads();
  }

  float bb[4];
  #pragma unroll
  for (int nt = 0; nt < 4; ++nt) bb[nt] = bias[n0 + wc + nt * 16 + c];

  float ns[4][4];
  #pragma unroll
  for (int mt = 0; mt < 4; ++mt)
    #pragma unroll
    for (int r = 0; r < 4; ++r) ns[mt][r] = 0.f;

  #pragma unroll
  for (int mt = 0; mt < 4; ++mt) {
    #pragma unroll
    for (int nt = 0; nt < 4; ++nt) {
      const int n = n0 + wc + nt * 16 + c;
      const int h = n >> 6, d = n & 63;
      #pragma unroll
      for (int r = 0; r < 4; ++r) {
        const int m = m0 + wr + mt * 16 + G * 4 + r;
        const int b = m >> 12, l = m & (LSEQ - 1);
        const float val = acc[mt][nt][r] + bb[nt];
        dst[((size_t)((b << 4) + h) * LSEQ + l) * HD + d] = f2bf(val * oscale);
        ns[mt][r] = fmaf(val, val, ns[mt][r]);
      }
    }
  }
  if (norms) {
    #pragma unroll
    for (int mt = 0; mt < 4; ++mt)
      #pragma unroll
      for (int r = 0; r < 4; ++r) {
        float v = ns[mt][r];
        v += __shfl_xor(v, 1); v += __shfl_xor(v, 2);
        v += __shfl_xor(v, 4); v += __shfl_xor(v, 8);
        ns[mt][r] = v;
      }
    if (c == 0) {
      const int h = (n0 + wc) >> 6;
      #pragma unroll
      for (int mt = 0; mt < 4; ++mt)
        #pragma unroll
        for (int r = 0; r < 4; ++r) {
          const int m = m0 + wr + mt * 16 + G * 4 + r;
          const int b = m >> 12, l = m & (LSEQ - 1);
          norms[(((size_t)((b << 4) + h)) << 12) + l] = ns[mt][r];
        }
    }
  }
}

// ---------------------------------------------------------------------------
// V projection body: transposed per-head out [bh*64+d][4096] via LDS T.
// ---------------------------------------------------------------------------
__device__ __forceinline__ void proj_v_body(
    u16* smem, const u16* __restrict__ Xb, const u16* __restrict__ Wb,
    const float* __restrict__ bias, u16* __restrict__ VgT, int bx, int ny)
{
  u16* As = smem;
  u16* Bs = smem + 4096;
  const int tid = threadIdx.x;
  const int m0 = bx * 128, n0 = ny * 128;
  const int wid = tid >> 6, lane = tid & 63;
  const int wr = (wid >> 1) * 64, wc = (wid & 1) * 64;
  const int c = lane & 15, G = lane >> 4;

  int Rr[2], Cr[2];
  #pragma unroll
  for (int rr = 0; rr < 2; ++rr) inv_swz((tid + rr * 256) * 8, Rr[rr], Cr[rr]);

  f32x4 acc[4][4];
  #pragma unroll
  for (int mt = 0; mt < 4; ++mt)
    #pragma unroll
    for (int nt = 0; nt < 4; ++nt)
      acc[mt][nt] = (f32x4){0.f, 0.f, 0.f, 0.f};

  for (int k0 = 0; k0 < DM; k0 += 32) {
    #pragma unroll
    for (int rr = 0; rr < 2; ++rr) {
      const size_t goA = (size_t)(m0 + Rr[rr]) * DM + k0 + Cr[rr] * 8;
      const size_t goB = (size_t)(n0 + Rr[rr]) * DM + k0 + Cr[rr] * 8;
      const int lb = wid * 512 + rr * 2048;
      gl16(Xb + goA, As + lb);
      gl16(Wb + goB, Bs + lb);
    }
    __syncthreads();

    short8v af[4], bf[4];
    #pragma unroll
    for (int mt = 0; mt < 4; ++mt) {
      const int m = wr + mt * 16 + c;
      af[mt] = *reinterpret_cast<const short8v*>(As + ((m * 32 + G * 8) ^ ((m & 7) << 3)));
      const int n = wc + mt * 16 + c;
      bf[mt] = *reinterpret_cast<const short8v*>(Bs + ((n * 32 + G * 8) ^ ((n & 7) << 3)));
    }
    #pragma unroll
    for (int mt = 0; mt < 4; ++mt)
      #pragma unroll
      for (int nt = 0; nt < 4; ++nt)
        acc[mt][nt] = __builtin_amdgcn_mfma_f32_16x16x32_bf16(af[mt], bf[nt], acc[mt][nt], 0, 0, 0);
    __syncthreads();
  }

  float bb[4];
  #pragma unroll
  for (int nt = 0; nt < 4; ++nt) bb[nt] = bias[n0 + wc + nt * 16 + c];

  #pragma unroll
  for (int mt = 0; mt < 4; ++mt) {
    #pragma unroll
    for (int nt = 0; nt < 4; ++nt) {
      const int n = wc + nt * 16 + c;
      const int mloc = wr + mt * 16 + G * 4;
      short4v pv;
      #pragma unroll
      for (int r = 0; r < 4; ++r) pv[r] = (short)f2bf(acc[mt][nt][r] + bb[nt]);
      *reinterpret_cast<short4v*>(smem + n * 136 + mloc) = pv;
    }
  }
  __syncthreads();
  const int bb2 = m0 >> 12;
  const int ml0 = m0 & (LSEQ - 1);
  #pragma unroll
  for (int uu = 0; uu < 8; ++uu) {
    const int u = uu * 256 + tid;
    const int n = u >> 4, kg = u & 15;
    short8v vvv = *reinterpret_cast<const short8v*>(smem + n * 136 + kg * 8);
    const int h = (n0 + n) >> 6, d = (n0 + n) & 63;
    *reinterpret_cast<short8v*>(
        VgT + ((size_t)((bb2 << 4) + h) * HD + d) * LSEQ + ml0 + kg * 8) = vvv;
  }
}

// ---------------------------------------------------------------------------
// Fused projection: by < 8 -> Q (scaled, + norms); 8..15 -> V; >=16 -> K.
// ---------------------------------------------------------------------------
__global__ __launch_bounds__(256) void gemm_proj(
    const u16* __restrict__ Xb,
    const u16* __restrict__ Wqb, const u16* __restrict__ Wkb, const u16* __restrict__ Wvb,
    const float* __restrict__ bq, const float* __restrict__ bk, const float* __restrict__ bv,
    u16* __restrict__ Qbb, float* __restrict__ norms,
    u16* __restrict__ Kb, u16* __restrict__ VgT)
{
  __shared__ __align__(16) u16 smem[17408];   // 34816 B union
  const int by = blockIdx.y;
  const int bx = blockIdx.x;
  if (by < 8) {
    proj_sh_body(smem, Xb, Wqb, bq, Qbb, norms, QSCALE, bx, by);
  } else if (by < 16) {
    proj_v_body(smem, Xb, Wvb, bv, VgT, bx, by - 8);
  } else {
    proj_sh_body(smem, Xb, Wkb, bk, Kb, nullptr, 1.0f, bx, by - 16);
  }
}

// ---------------------------------------------------------------------------
// Output GEMM: out = O1b(bf16) @ Wob^T + bo, fp32 row-major out.
// ---------------------------------------------------------------------------
__global__ __launch_bounds__(256) void gemm_out(
    const u16* __restrict__ Xb, const u16* __restrict__ Wb,
    const float* __restrict__ bias, float* __restrict__ Y)
{
  __shared__ u16 As[128 * 32];
  __shared__ u16 Bs[128 * 32];
  const int tid = threadIdx.x;
  const int m0 = blockIdx.x * 128, n0 = blockIdx.y * 128;
  const int wid = tid >> 6, lane = tid & 63;
  const int wr = (wid >> 1) * 64, wc = (wid & 1) * 64;
  const int c = lane & 15, G = lane >> 4;

  int Rr[2], Cr[2];
  #pragma unroll
  for (int rr = 0; rr < 2; ++rr) inv_swz((tid + rr * 256) * 8, Rr[rr], Cr[rr]);

  f32x4 acc[4][4];
  #pragma unroll
  for (int mt = 0; mt < 4; ++mt)
    #pragma unroll
    for (int nt = 0; nt < 4; ++nt)
      acc[mt][nt] = (f32x4){0.f, 0.f, 0.f, 0.f};

  for (int k0 = 0; k0 < DM; k0 += 32) {
    #pragma unroll
    for (int rr = 0; rr < 2; ++rr) {
      const size_t goA = (size_t)(m0 + Rr[rr]) * DM + k0 + Cr[rr] * 8;
      const size_t goB = (size_t)(n0 + Rr[rr]) * DM + k0 + Cr[rr] * 8;
      const int lb = wid * 512 + rr * 2048;
      gl16(Xb + goA, As + lb);
      gl16(Wb + goB, Bs + lb);
    }
    __syncthreads();

    short8v af[4], bf[4];
    #pragma unroll
    for (int mt = 0; mt < 4; ++mt) {
      const int m = wr + mt * 16 + c;
      af[mt] = *reinterpret_cast<const short8v*>(As + ((m * 32 + G * 8) ^ ((m & 7) << 3)));
      const int n = wc + mt * 16 + c;
      bf[mt] = *reinterpret_cast<const short8v*>(Bs + ((n * 32 + G * 8) ^ ((n & 7) << 3)));
    }
    #pragma unroll
    for (int mt = 0; mt < 4; ++mt)
      #pragma unroll
      for (int nt = 0; nt < 4; ++nt)
        acc[mt][nt] = __builtin_amdgcn_mfma_f32_16x16x32_bf16(af[mt], bf[nt], acc[mt][nt], 0, 0, 0);
    __syncthreads();
  }

  float bb[4];
  #pragma unroll
  for (int nt = 0; nt < 4; ++nt) bb[nt] = bias[n0 + wc + nt * 16 + c];

  #pragma unroll
  for (int mt = 0; mt < 4; ++mt) {
    #pragma unroll
    for (int nt = 0; nt < 4; ++nt) {
      const int n = n0 + wc + nt * 16 + c;
      #pragma unroll
      for (int r = 0; r < 4; ++r) {
        const int m = m0 + wr + mt * 16 + G * 4 + r;
        Y[(size_t)m * DM + n] = acc[mt][nt][r] + bb[nt];
      }
    }
  }
}

// ---------------------------------------------------------------------------
// selectA: radix-select the 819th approx norm A; classify rows:
//   definite-in (> A(1+3b)) -> tix; uncertain (>= A(1-3b)) -> ukeys.
// ---------------------------------------------------------------------------
__global__ __launch_bounds__(1024) void selectA(
    const float* __restrict__ norms, int* __restrict__ tix,
    u64* __restrict__ ukeys, int* __restrict__ Dcnt, int* __restrict__ Ucnt)
{
  __shared__ unsigned int keys[LSEQ];
  __shared__ unsigned int hist[256];
  __shared__ unsigned int sh_b, sh_above;
  __shared__ unsigned int cD, cU;

  const int tid = threadIdx.x;
  const int bh = blockIdx.x;

  for (int l = tid; l < LSEQ; l += 1024)
    keys[l] = __float_as_uint(norms[bh * LSEQ + l]);
  if (tid == 0) { cD = 0; cU = 0; }
  __syncthreads();

  unsigned int prefix = 0, rem = TOPU;
  for (int shift = 24; shift >= 0; shift -= 8) {
    if (tid < 256) hist[tid] = 0;
    __syncthreads();
    for (int l = tid; l < LSEQ; l += 1024) {
      const unsigned int k = keys[l];
      const bool in = (shift == 24) || ((k >> (shift + 8)) == prefix);
      if (in) atomicAdd(&hist[(k >> shift) & 255], 1);
    }
    __syncthreads();
    if (tid == 0) {
      unsigned int cum = 0; int b = 255;
      for (; b > 0; --b) {
        const unsigned int h = hist[b];
        if (cum + h >= rem) break;
        cum += h;
      }
      sh_b = (unsigned int)b; sh_above = cum;
    }
    __syncthreads();
    prefix = (prefix << 8) | sh_b;
    rem -= sh_above;
    __syncthreads();
  }

  const float A = __uint_as_float(prefix);
  const float Whi = A * (1.0f + 3.0f * BAND);
  const float Wlo = A * (1.0f - 3.0f * BAND);

  for (int l = tid; l < LSEQ; l += 1024) {
    const float v = __uint_as_float(keys[l]);
    if (v > Whi) {
      const unsigned p = atomicAdd(&cD, 1);
      tix[bh * TOPU + p] = l;
    } else if (v >= Wlo) {
      const unsigned u = atomicAdd(&cU, 1);
      if (u < UCAP)
        ukeys[(size_t)bh * UCAP + u] =
            ((u64)keys[l] << 32) | (unsigned int)(~l);
    }
  }
  __syncthreads();
  if (tid == 0) {
    Dcnt[bh] = (int)cD;
    Ucnt[bh] = (int)(cU < UCAP ? cU : UCAP);
  }
}

// ---------------------------------------------------------------------------
// Recompute exact fp32 norms for uncertain rows -- ONE BLOCK PER ROW,
// lanes sweep k (coalesced W reads).
// ---------------------------------------------------------------------------
__global__ __launch_bounds__(256) void recompute_norms(
    const float* __restrict__ x, const float* __restrict__ Wq,
    const float* __restrict__ bq, u64* __restrict__ ukeys,
    const int* __restrict__ Ucnt)
{
  const int bh = blockIdx.x;
  const int r  = blockIdx.y;
  if (r >= Ucnt[bh]) return;

  __shared__ float xs[DM];       // 4 KB
  __shared__ float wsum[4];
  const int tid = threadIdx.x;
  const int wid = tid >> 6, lane = tid & 63;
  const int h = bh & 15, bI = bh >> 4;

  const u64 key = ukeys[(size_t)bh * UCAP + r];
  const int row = (int)(~(unsigned int)(key & 0xffffffffu));

  *reinterpret_cast<float4*>(xs + tid * 4) =
      *reinterpret_cast<const float4*>(
          x + (size_t)(bI * LSEQ + row) * DM + tid * 4);
  __syncthreads();

  float sq = 0.f;
  #pragma unroll 4
  for (int i = 0; i < 16; ++i) {
    const int d = wid * 16 + i;
    const float* wp = Wq + (size_t)(h * 64 + d) * DM;
    float s = 0.f;
    #pragma unroll
    for (int ch = 0; ch < 4; ++ch) {
      const float4 wv = *reinterpret_cast<const float4*>(wp + ch * 256 + lane * 4);
      const float4 xv = *reinterpret_cast<const float4*>(xs + ch * 256 + lane * 4);
      s = fmaf(wv.x, xv.x, s); s = fmaf(wv.y, xv.y, s);
      s = fmaf(wv.z, xv.z, s); s = fmaf(wv.w, xv.w, s);
    }
    s += __shfl_xor(s, 1);  s += __shfl_xor(s, 2);  s += __shfl_xor(s, 4);
    s += __shfl_xor(s, 8);  s += __shfl_xor(s, 16); s += __shfl_xor(s, 32);
    if (lane == 0) {
      const float q = s + bq[h * 64 + d];
      sq = fmaf(q, q, sq);
    }
  }
  if (lane == 0) wsum[wid] = sq;
  __syncthreads();
  if (tid == 0) {
    const float tot = wsum[0] + wsum[1] + wsum[2] + wsum[3];
    ukeys[(size_t)bh * UCAP + r] =
        ((u64)__float_as_uint(tot) << 32) | (key & 0xffffffffu);
  }
}

// ---------------------------------------------------------------------------
// selectB: bitonic sort (desc value, asc index) the uncertain keys (now with
// exact norms), append the top (819 - D) to tix.
// ---------------------------------------------------------------------------
__global__ __launch_bounds__(1024) void selectB(
    const u64* __restrict__ ukeys, const int* __restrict__ Dcnt,
    const int* __restrict__ Ucnt, int* __restrict__ tix)
{
  __shared__ u64 sk[UCAP];
  const int bh = blockIdx.x;
  const int U = Ucnt[bh], D = Dcnt[bh];
  const int need = TOPU - D;
  const int tid = threadIdx.x;

  sk[tid] = (tid < U) ? ukeys[(size_t)bh * UCAP + tid] : 0ULL;
  __syncthreads();
  for (int k = 2; k <= UCAP; k <<= 1) {
    for (int j = k >> 1; j > 0; j >>= 1) {
      const int ixj = tid ^ j;
      if (ixj > tid) {
        const bool desc = ((tid & k) == 0);
        const u64 a = sk[tid], b = sk[ixj];
        if (desc ? (a < b) : (a > b)) { sk[tid] = b; sk[ixj] = a; }
      }
      __syncthreads();
    }
  }
  if (tid < need)
    tix[bh * TOPU + D + tid] =
        (tid < U) ? (int)(~(unsigned int)(sk[tid] & 0xffffffffu)) : 0;
}

// ---------------------------------------------------------------------------
// MFMA flash attention, split-K x4, bf16 partial O + fp32 (m,lsum).
// Q pre-scaled by 0.125*log2e at projection -> raw fragments, native exp2
// softmax (m, lsum in log2 domain), cvt_pk P conversion, defer-max.
// ---------------------------------------------------------------------------
__global__ __launch_bounds__(256) void attn_mfma(
    const u16* __restrict__ Qbb, const u16* __restrict__ Kg,
    const u16* __restrict__ VgT, const int* __restrict__ tix,
    u16* __restrict__ OpartB, float* __restrict__ MLpart)
{
  __shared__ u16 Kc[128 * 64];
  __shared__ u16 Vt[64 * 128];
  __shared__ u16 Pt[4][16 * 136];

  const int tid = threadIdx.x;
  const int wid = tid >> 6, lane = tid & 63;
  const int c = lane & 15, G = lane >> 4;

  const int l = blockIdx.x;
  const int grp = l >> 3;                  // 0..207
  const int bh = (grp / 52) * 8 + (l & 7);
  const int rem = grp % 52;
  const int qb = rem >> 2, ks = rem & 3;

  const size_t bhL = (size_t)bh * LSEQ;
  const int rglob = qb * 64 + wid * 16 + c;
  const int rowidx = (rglob < TOPU) ? tix[bh * TOPU + rglob] : -1;

  short8v qf[2];
  #pragma unroll
  for (int kf = 0; kf < 2; ++kf) {
    if (rowidx >= 0) {
      qf[kf] = *reinterpret_cast<const short8v*>(
          Qbb + (bhL + rowidx) * HD + kf * 32 + G * 8);
    } else {
      short8v v;
      #pragma unroll
      for (int j = 0; j < 8; ++j) v[j] = 0;
      qf[kf] = v;
    }
  }

  float m = -1e30f, lsum = 0.f;
  f32x4 oacc[4];
  #pragma unroll
  for (int dt = 0; dt < 4; ++dt) oacc[dt] = (f32x4){0.f, 0.f, 0.f, 0.f};

  const int ko0 = ks * (LSEQ / NSEG);
  const int wbase = (tid & ~63) * 8;
  const int csw = c & 7;
  for (int t = 0; t < LSEQ / NSEG / 128; ++t) {
    const int ko = ko0 + t * 128;
    #pragma unroll
    for (int uu = 0; uu < 4; ++uu) {
      const int S = (uu * 256 + tid) * 8;
      const int key = S >> 6, dgk = ((S >> 3) & 7) ^ (key & 7);
      gl16(Kg + (bhL + ko + key) * HD + dgk * 8, Kc + uu * 2048 + wbase);
      const int d = S >> 7, kgv = ((S >> 3) & 15) ^ (d & 7);
      gl16(VgT + ((size_t)bh * HD + d) * LSEQ + ko + kgv * 8, Vt + uu * 2048 + wbase);
    }
    __syncthreads();

    f32x4 sacc[8];
    __builtin_amdgcn_s_setprio(1);
    #pragma unroll
    for (int kt = 0; kt < 8; ++kt) {
      const int key = kt * 16 + c;
      short8v kb0 = *reinterpret_cast<const short8v*>(
          Kc + key * 64 + (((0 + G) ^ (key & 7)) << 3));
      short8v kb1 = *reinterpret_cast<const short8v*>(
          Kc + key * 64 + (((4 + G) ^ (key & 7)) << 3));
      f32x4 s = (f32x4){0.f, 0.f, 0.f, 0.f};
      s = __builtin_amdgcn_mfma_f32_16x16x32_bf16(kb0, qf[0], s, 0, 0, 0);
      s = __builtin_amdgcn_mfma_f32_16x16x32_bf16(kb1, qf[1], s, 0, 0, 0);
      sacc[kt] = s;
    }
    __builtin_amdgcn_s_setprio(0);

    float smax = -1e30f;
    #pragma unroll
    for (int kt = 0; kt < 8; ++kt) {
      float a0 = fmaxf(sacc[kt][0], sacc[kt][1]);
      float a1 = fmaxf(sacc[kt][2], sacc[kt][3]);
      smax = fmaxf(smax, fmaxf(a0, a1));
    }
    smax = fmaxf(smax, __shfl_xor(smax, 16));
    smax = fmaxf(smax, __shfl_xor(smax, 32));

    // defer-max (T13): only rescale when some lane's max grew past THR=8
    if (!__all(smax - m <= 8.0f)) {
      const float mnew = fmaxf(m, smax);
      const float corr = fexp2(m - mnew);
      lsum *= corr;
      #pragma unroll
      for (int dt = 0; dt < 4; ++dt) oacc[dt] *= corr;
      m = mnew;
    }

    float ssum = 0.f;
    #pragma unroll
    for (int kt = 0; kt < 8; ++kt) {
      float p0 = fexp2(sacc[kt][0] - m);
      float p1 = fexp2(sacc[kt][1] - m);
      float p2 = fexp2(sacc[kt][2] - m);
      float p3 = fexp2(sacc[kt][3] - m);
      ssum += (p0 + p1) + (p2 + p3);
      unsigned pk01, pk23;
      asm("v_cvt_pk_bf16_f32 %0, %1, %2" : "=v"(pk01) : "v"(p0), "v"(p1));
      asm("v_cvt_pk_bf16_f32 %0, %1, %2" : "=v"(pk23) : "v"(p2), "v"(p3));
      uint2 pv; pv.x = pk01; pv.y = pk23;
      *reinterpret_cast<uint2*>(
          &Pt[wid][c * 136 + ((kt ^ csw) << 4) + G * 4]) = pv;
    }
    ssum += __shfl_xor(ssum, 16);
    ssum += __shfl_xor(ssum, 32);
    lsum += ssum;

    __builtin_amdgcn_s_setprio(1);
    #pragma unroll
    for (int kf = 0; kf < 4; ++kf) {
      short8v pf = *reinterpret_cast<const short8v*>(
          &Pt[wid][c * 136 + (((2 * kf + (G >> 1)) ^ csw) << 4) + (G & 1) * 8]);
      #pragma unroll
      for (int dt = 0; dt < 4; ++dt) {
        const int d = dt * 16 + c;
        short8v vf = *reinterpret_cast<const short8v*>(
            Vt + d * 128 + (((kf * 4 + G) ^ (d & 7)) << 3));
        oacc[dt] = __builtin_amdgcn_mfma_f32_16x16x32_bf16(vf, pf, oacc[dt], 0, 0, 0);
      }
    }
    __builtin_amdgcn_s_setprio(0);
    __syncthreads();
  }

  const int q = wid * 16 + c;
  const size_t pb = ((size_t)((bh * 13 + qb) * NSEG + ks)) * 64 + q;
  u16* op = OpartB + pb * 64;
  #pragma unroll
  for (int dt = 0; dt < 4; ++dt) {
    short4v o;
    o[0] = (short)f2bf(oacc[dt][0]); o[1] = (short)f2bf(oacc[dt][1]);
    o[2] = (short)f2bf(oacc[dt][2]); o[3] = (short)f2bf(oacc[dt][3]);
    *reinterpret_cast<short4v*>(op + dt * 16 + G * 4) = o;
  }
  if (G == 0) {
    MLpart[pb * 2]     = m;     // log2-domain running max
    MLpart[pb * 2 + 1] = lsum;
  }
}

// ---------------------------------------------------------------------------
// 4-way split-K combine (log2-domain m): O = sum Oi*ci / sum li*ci, bf16 out.
// ---------------------------------------------------------------------------
__global__ __launch_bounds__(256) void attn_combine(
    const u16* __restrict__ OpartB, const float* __restrict__ MLpart,
    const int* __restrict__ tix, u16* __restrict__ O1b)
{
  const int bq = blockIdx.x;
  const int bh = bq / 13, qb = bq % 13;
  const int tid = threadIdx.x;
  const int q = tid >> 2, dq = (tid & 3) * 16;
  const int rglob = qb * 64 + q;
  if (rglob >= TOPU) return;
  const int rowidx = tix[bh * TOPU + rglob];

  size_t p[NSEG];
  float mi[NSEG], li[NSEG];
  #pragma unroll
  for (int i = 0; i < NSEG; ++i) {
    p[i] = ((size_t)bq * NSEG + i) * 64 + q;
    mi[i] = MLpart[p[i] * 2];
    li[i] = MLpart[p[i] * 2 + 1];
  }
  float mx = fmaxf(fmaxf(mi[0], mi[1]), fmaxf(mi[2], mi[3]));
  float ci[NSEG], lsum = 0.f;
  #pragma unroll
  for (int i = 0; i < NSEG; ++i) { ci[i] = fexp2(mi[i] - mx); lsum += li[i] * ci[i]; }
  const float linv = 1.0f / lsum;

  float acc[16];
  #pragma unroll
  for (int j = 0; j < 16; ++j) acc[j] = 0.f;
  #pragma unroll
  for (int i = 0; i < NSEG; ++i) {
    const u16* src = OpartB + p[i] * 64 + dq;
    #pragma unroll
    for (int j = 0; j < 16; ++j) acc[j] += bf2f(src[j]) * ci[i];
  }

  const int b = bh >> 4, h = bh & 15;
  u16* dst = O1b + (size_t)(b * LSEQ + rowidx) * DM + h * HD + dq;
  #pragma unroll
  for (int j0 = 0; j0 < 16; j0 += 4) {
    short4v o;
    #pragma unroll
    for (int j = 0; j < 4; ++j) o[j] = (short)f2bf(acc[j0 + j] * linv);
    *reinterpret_cast<short4v*>(dst + j0) = o;
  }
}

// ---------------------------------------------------------------------------
extern "C" void kernel_launch(void* const* d_in, const int* in_sizes, int n_in,
                              void* d_out, int out_size, void* d_ws, size_t ws_size,
                              hipStream_t stream) {
  const float* x  = (const float*)d_in[0];
  const float* Wq = (const float*)d_in[1];
  const float* bq = (const float*)d_in[2];
  const float* Wk = (const float*)d_in[3];
  const float* bk = (const float*)d_in[4];
  const float* Wv = (const float*)d_in[5];
  const float* bv = (const float*)d_in[6];
  const float* Wo = (const float*)d_in[7];
  const float* bo = (const float*)d_in[8];
  float* out = (float*)d_out;

  char* w = (char*)d_ws;
  u16* xb   = (u16*)w;  w += (size_t)MROWS * DM * 2;           // 16 MB -> OpartB/ML
  u16* Qbb  = (u16*)w;  w += (size_t)BHT * LSEQ * HD * 2;      // 16 MB
  u16* Kb   = (u16*)w;  w += (size_t)BHT * LSEQ * HD * 2;      // 16 MB
  u16* VgT  = (u16*)w;  w += (size_t)BHT * HD * LSEQ * 2;      // 16 MB
  u16* O1b  = (u16*)w;  w += (size_t)MROWS * DM * 2;           // 16 MB
  u16* Wqb  = (u16*)w;  w += (size_t)DM * DM * 2;              // 2 MB
  u16* Wkb  = (u16*)w;  w += (size_t)DM * DM * 2;
  u16* Wvb  = (u16*)w;  w += (size_t)DM * DM * 2;
  u16* Wob  = (u16*)w;  w += (size_t)DM * DM * 2;
  float* norms = (float*)w; w += (size_t)BHT * LSEQ * 4;       // 512 KB
  int* tix  = (int*)w;  w += (size_t)BHT * TOPU * 4;           // 105 KB
  u64* ukeys = (u64*)w; w += (size_t)BHT * UCAP * 8;           // 256 KB
  int* Dcnt = (int*)w;  w += 128;
  int* Ucnt = (int*)w;  w += 128;

  // attn partials alias xb (dead after gemm_proj): 13.6 + 0.85 MB <= 16 MB
  u16*   OpartB = xb;
  const int NPB = BHT * 13 * NSEG * 64;
  float* MLpart = (float*)(OpartB + (size_t)NPB * 64);

  prep_all<<<6144, 256, 0, stream>>>(x, Wq, Wk, Wv, Wo, xb, Wqb, Wkb, Wvb, Wob);

  gemm_proj<<<dim3(64, 24), 256, 0, stream>>>(
      xb, Wqb, Wkb, Wvb, bq, bk, bv, Qbb, norms, Kb, VgT);

  selectA<<<BHT, 1024, 0, stream>>>(norms, tix, ukeys, Dcnt, Ucnt);
  recompute_norms<<<dim3(BHT, UCAP), 256, 0, stream>>>(x, Wq, bq, ukeys, Ucnt);
  selectB<<<BHT, 1024, 0, stream>>>(ukeys, Dcnt, Ucnt, tix);

  hipMemsetAsync(O1b, 0, (size_t)MROWS * DM * 2, stream);

  attn_mfma<<<BHT * 13 * NSEG, 256, 0, stream>>>(Qbb, Kb, VgT, tix, OpartB, MLpart);
  attn_combine<<<BHT * 13, 256, 0, stream>>>(OpartB, MLpart, tix, O1b);

  gemm_out<<<dim3(MROWS / 128, DM / 128), 256, 0, stream>>>(O1b, Wob, bo, out);
}

// Round 17
// 259.653 us; speedup vs baseline: 1.0243x; 1.0243x over previous
//
#include <hip/hip_runtime.h>
#include <cstddef>
#include <cstdint>

constexpr int LSEQ = 4096;
constexpr int DM   = 1024;
constexpr int HD   = 64;
constexpr int BHT  = 32;     // B*H
constexpr int TOPU = 819;
constexpr int MROWS = 8192;  // B*L
constexpr int NSEG = 4;      // attention split-K segments
constexpr int UCAP = 1024;   // uncertain-row capacity per bh
#define BAND 2.4e-3f         // 6-sigma bound on approx-norm relative error
#define QSCALE 0.180336880f  // 0.125 * log2(e): softmax scale in log2 domain

typedef unsigned short u16;
typedef unsigned long long u64;
typedef __attribute__((ext_vector_type(8))) short short8v;  // 8 bf16
typedef __attribute__((ext_vector_type(4))) short short4v;  // 4 bf16
typedef __attribute__((ext_vector_type(4))) float f32x4;

__device__ __forceinline__ u16 f2bf(float f) {
  uint32_t u = __float_as_uint(f);
  u += 0x7fffu + ((u >> 16) & 1u);   // RNE
  return (u16)(u >> 16);
}
__device__ __forceinline__ float bf2f(u16 h) {
  return __uint_as_float(((uint32_t)h) << 16);
}
// native 2^x (v_exp_f32 IS exp2)
__device__ __forceinline__ float fexp2(float x) {
  float r; asm("v_exp_f32 %0, %1" : "=v"(r) : "v"(x)); return r;
}

// async 16B global -> LDS (DMA).  LDS dest wave-uniform base; HW adds lane*16.
__device__ __forceinline__ void gl16(const void* g, void* l) {
  __builtin_amdgcn_global_load_lds(
      (const __attribute__((address_space(1))) void*)g,
      (__attribute__((address_space(3))) void*)l, 16, 0, 0);
}

// Inverse of the LDS swizzle e = (R*32 + C*8) ^ ((R&7)<<3) for linear slot S.
__device__ __forceinline__ void inv_swz(int S, int& R, int& C) {
  const int R0 = ((S >> 5) ^ (S >> 7)) & 1;
  const int R1 = (S >> 6) & 1;
  R = ((S >> 6) << 1) | R0;
  C = (((S >> 3) & 1) ^ R0) | ((((S >> 4) & 1) ^ R1) << 1);
}

// ---------------------------------------------------------------------------
// Prep: bf16 conversions (x, Wq*QSCALE, Wk, Wv, Wo).  Wq is PRE-SCALED so the
// proj epilogue stays multiply-free (round-16 lesson: runtime oscale pushed
// proj from 84->88 VGPR -> 6->5 waves/SIMD occupancy cliff, +12 us).
// ---------------------------------------------------------------------------
__device__ __forceinline__ void conv_body(const float* src, u16* dst, int i,
                                          float sc) {
  const float4 a = *reinterpret_cast<const float4*>(src + (size_t)i * 8);
  const float4 b = *reinterpret_cast<const float4*>(src + (size_t)i * 8 + 4);
  short8v v;
  v[0] = (short)f2bf(a.x * sc); v[1] = (short)f2bf(a.y * sc);
  v[2] = (short)f2bf(a.z * sc); v[3] = (short)f2bf(a.w * sc);
  v[4] = (short)f2bf(b.x * sc); v[5] = (short)f2bf(b.y * sc);
  v[6] = (short)f2bf(b.z * sc); v[7] = (short)f2bf(b.w * sc);
  *reinterpret_cast<short8v*>(dst + (size_t)i * 8) = v;
}

__global__ __launch_bounds__(256) void prep_all(
    const float* __restrict__ x,  const float* __restrict__ Wq,
    const float* __restrict__ Wk, const float* __restrict__ Wv,
    const float* __restrict__ Wo,
    u16* __restrict__ xb, u16* __restrict__ Wqb, u16* __restrict__ Wkb,
    u16* __restrict__ Wvb, u16* __restrict__ Wob)
{
  const int NX = MROWS * DM / 8;   // 1048576
  const int NW = DM * DM / 8;      // 131072
  int i = blockIdx.x * 256 + threadIdx.x;
  if (i < NX)  { conv_body(x,  xb,  i, 1.0f); return; }
  i -= NX;
  if (i < NW)  { conv_body(Wq, Wqb, i, QSCALE); return; }
  i -= NW;
  if (i < NW)  { conv_body(Wk, Wkb, i, 1.0f); return; }
  i -= NW;
  if (i < NW)  { conv_body(Wv, Wvb, i, 1.0f); return; }
  i -= NW;
  if (i < NW)  { conv_body(Wo, Wob, i, 1.0f); }
}

// ---------------------------------------------------------------------------
// Single-product projection body, split-head bf16 out; optional fused norms
// (Q mode: SCALEB scales the bias by QSCALE at load -- compile-time literal,
// epilogue stays the round-14 84-VGPR form).
// ---------------------------------------------------------------------------
template<bool SCALEB>
__device__ __forceinline__ void proj_sh_body(
    u16* smem, const u16* __restrict__ Xb, const u16* __restrict__ Wb,
    const float* __restrict__ bias, u16* __restrict__ dst,
    float* __restrict__ norms, int bx, int ny)
{
  u16* As = smem;
  u16* Bs = smem + 4096;
  const int tid = threadIdx.x;
  const int m0 = bx * 128, n0 = ny * 128;
  const int wid = tid >> 6, lane = tid & 63;
  const int wr = (wid >> 1) * 64, wc = (wid & 1) * 64;
  const int c = lane & 15, G = lane >> 4;

  int Rr[2], Cr[2];
  #pragma unroll
  for (int rr = 0; rr < 2; ++rr) inv_swz((tid + rr * 256) * 8, Rr[rr], Cr[rr]);

  f32x4 acc[4][4];
  #pragma unroll
  for (int mt = 0; mt < 4; ++mt)
    #pragma unroll
    for (int nt = 0; nt < 4; ++nt)
      acc[mt][nt] = (f32x4){0.f, 0.f, 0.f, 0.f};

  for (int k0 = 0; k0 < DM; k0 += 32) {
    #pragma unroll
    for (int rr = 0; rr < 2; ++rr) {
      const size_t goA = (size_t)(m0 + Rr[rr]) * DM + k0 + Cr[rr] * 8;
      const size_t goB = (size_t)(n0 + Rr[rr]) * DM + k0 + Cr[rr] * 8;
      const int lb = wid * 512 + rr * 2048;
      gl16(Xb + goA, As + lb);
      gl16(Wb + goB, Bs + lb);
    }
    __syncthreads();

    short8v af[4], bf[4];
    #pragma unroll
    for (int mt = 0; mt < 4; ++mt) {
      const int m = wr + mt * 16 + c;
      af[mt] = *reinterpret_cast<const short8v*>(As + ((m * 32 + G * 8) ^ ((m & 7) << 3)));
      const int n = wc + mt * 16 + c;
      bf[mt] = *reinterpret_cast<const short8v*>(Bs + ((n * 32 + G * 8) ^ ((n & 7) << 3)));
    }
    #pragma unroll
    for (int mt = 0; mt < 4; ++mt)
      #pragma unroll
      for (int nt = 0; nt < 4; ++nt)
        acc[mt][nt] = __builtin_amdgcn_mfma_f32_16x16x32_bf16(af[mt], bf[nt], acc[mt][nt], 0, 0, 0);
    __syncthreads();
  }

  float bb[4];
  #pragma unroll
  for (int nt = 0; nt < 4; ++nt) {
    bb[nt] = bias[n0 + wc + nt * 16 + c];
    if (SCALEB) bb[nt] *= QSCALE;
  }

  float ns[4][4];
  #pragma unroll
  for (int mt = 0; mt < 4; ++mt)
    #pragma unroll
    for (int r = 0; r < 4; ++r) ns[mt][r] = 0.f;

  #pragma unroll
  for (int mt = 0; mt < 4; ++mt) {
    #pragma unroll
    for (int nt = 0; nt < 4; ++nt) {
      const int n = n0 + wc + nt * 16 + c;
      const int h = n >> 6, d = n & 63;
      #pragma unroll
      for (int r = 0; r < 4; ++r) {
        const int m = m0 + wr + mt * 16 + G * 4 + r;
        const int b = m >> 12, l = m & (LSEQ - 1);
        const float val = acc[mt][nt][r] + bb[nt];
        dst[((size_t)((b << 4) + h) * LSEQ + l) * HD + d] = f2bf(val);
        ns[mt][r] = fmaf(val, val, ns[mt][r]);
      }
    }
  }
  if (norms) {
    #pragma unroll
    for (int mt = 0; mt < 4; ++mt)
      #pragma unroll
      for (int r = 0; r < 4; ++r) {
        float v = ns[mt][r];
        v += __shfl_xor(v, 1); v += __shfl_xor(v, 2);
        v += __shfl_xor(v, 4); v += __shfl_xor(v, 8);
        ns[mt][r] = v;
      }
    if (c == 0) {
      const int h = (n0 + wc) >> 6;
      #pragma unroll
      for (int mt = 0; mt < 4; ++mt)
        #pragma unroll
        for (int r = 0; r < 4; ++r) {
          const int m = m0 + wr + mt * 16 + G * 4 + r;
          const int b = m >> 12, l = m & (LSEQ - 1);
          norms[(((size_t)((b << 4) + h)) << 12) + l] = ns[mt][r];
        }
    }
  }
}

// ---------------------------------------------------------------------------
// V projection body: transposed per-head out [bh*64+d][4096] via LDS T.
// ---------------------------------------------------------------------------
__device__ __forceinline__ void proj_v_body(
    u16* smem, const u16* __restrict__ Xb, const u16* __restrict__ Wb,
    const float* __restrict__ bias, u16* __restrict__ VgT, int bx, int ny)
{
  u16* As = smem;
  u16* Bs = smem + 4096;
  const int tid = threadIdx.x;
  const int m0 = bx * 128, n0 = ny * 128;
  const int wid = tid >> 6, lane = tid & 63;
  const int wr = (wid >> 1) * 64, wc = (wid & 1) * 64;
  const int c = lane & 15, G = lane >> 4;

  int Rr[2], Cr[2];
  #pragma unroll
  for (int rr = 0; rr < 2; ++rr) inv_swz((tid + rr * 256) * 8, Rr[rr], Cr[rr]);

  f32x4 acc[4][4];
  #pragma unroll
  for (int mt = 0; mt < 4; ++mt)
    #pragma unroll
    for (int nt = 0; nt < 4; ++nt)
      acc[mt][nt] = (f32x4){0.f, 0.f, 0.f, 0.f};

  for (int k0 = 0; k0 < DM; k0 += 32) {
    #pragma unroll
    for (int rr = 0; rr < 2; ++rr) {
      const size_t goA = (size_t)(m0 + Rr[rr]) * DM + k0 + Cr[rr] * 8;
      const size_t goB = (size_t)(n0 + Rr[rr]) * DM + k0 + Cr[rr] * 8;
      const int lb = wid * 512 + rr * 2048;
      gl16(Xb + goA, As + lb);
      gl16(Wb + goB, Bs + lb);
    }
    __syncthreads();

    short8v af[4], bf[4];
    #pragma unroll
    for (int mt = 0; mt < 4; ++mt) {
      const int m = wr + mt * 16 + c;
      af[mt] = *reinterpret_cast<const short8v*>(As + ((m * 32 + G * 8) ^ ((m & 7) << 3)));
      const int n = wc + mt * 16 + c;
      bf[mt] = *reinterpret_cast<const short8v*>(Bs + ((n * 32 + G * 8) ^ ((n & 7) << 3)));
    }
    #pragma unroll
    for (int mt = 0; mt < 4; ++mt)
      #pragma unroll
      for (int nt = 0; nt < 4; ++nt)
        acc[mt][nt] = __builtin_amdgcn_mfma_f32_16x16x32_bf16(af[mt], bf[nt], acc[mt][nt], 0, 0, 0);
    __syncthreads();
  }

  float bb[4];
  #pragma unroll
  for (int nt = 0; nt < 4; ++nt) bb[nt] = bias[n0 + wc + nt * 16 + c];

  #pragma unroll
  for (int mt = 0; mt < 4; ++mt) {
    #pragma unroll
    for (int nt = 0; nt < 4; ++nt) {
      const int n = wc + nt * 16 + c;
      const int mloc = wr + mt * 16 + G * 4;
      short4v pv;
      #pragma unroll
      for (int r = 0; r < 4; ++r) pv[r] = (short)f2bf(acc[mt][nt][r] + bb[nt]);
      *reinterpret_cast<short4v*>(smem + n * 136 + mloc) = pv;
    }
  }
  __syncthreads();
  const int bb2 = m0 >> 12;
  const int ml0 = m0 & (LSEQ - 1);
  #pragma unroll
  for (int uu = 0; uu < 8; ++uu) {
    const int u = uu * 256 + tid;
    const int n = u >> 4, kg = u & 15;
    short8v vvv = *reinterpret_cast<const short8v*>(smem + n * 136 + kg * 8);
    const int h = (n0 + n) >> 6, d = (n0 + n) & 63;
    *reinterpret_cast<short8v*>(
        VgT + ((size_t)((bb2 << 4) + h) * HD + d) * LSEQ + ml0 + kg * 8) = vvv;
  }
}

// ---------------------------------------------------------------------------
// Fused projection: by < 8 -> Q (prescaled W + scaled bias, + norms);
// 8..15 -> V; >=16 -> K.
// ---------------------------------------------------------------------------
__global__ __launch_bounds__(256) void gemm_proj(
    const u16* __restrict__ Xb,
    const u16* __restrict__ Wqb, const u16* __restrict__ Wkb, const u16* __restrict__ Wvb,
    const float* __restrict__ bq, const float* __restrict__ bk, const float* __restrict__ bv,
    u16* __restrict__ Qbb, float* __restrict__ norms,
    u16* __restrict__ Kb, u16* __restrict__ VgT)
{
  __shared__ __align__(16) u16 smem[17408];   // 34816 B union
  const int by = blockIdx.y;
  const int bx = blockIdx.x;
  if (by < 8) {
    proj_sh_body<true>(smem, Xb, Wqb, bq, Qbb, norms, bx, by);
  } else if (by < 16) {
    proj_v_body(smem, Xb, Wvb, bv, VgT, bx, by - 8);
  } else {
    proj_sh_body<false>(smem, Xb, Wkb, bk, Kb, nullptr, bx, by - 16);
  }
}

// ---------------------------------------------------------------------------
// Output GEMM: out = O1b(bf16) @ Wob^T + bo, fp32 row-major out.
// ---------------------------------------------------------------------------
__global__ __launch_bounds__(256) void gemm_out(
    const u16* __restrict__ Xb, const u16* __restrict__ Wb,
    const float* __restrict__ bias, float* __restrict__ Y)
{
  __shared__ u16 As[128 * 32];
  __shared__ u16 Bs[128 * 32];
  const int tid = threadIdx.x;
  const int m0 = blockIdx.x * 128, n0 = blockIdx.y * 128;
  const int wid = tid >> 6, lane = tid & 63;
  const int wr = (wid >> 1) * 64, wc = (wid & 1) * 64;
  const int c = lane & 15, G = lane >> 4;

  int Rr[2], Cr[2];
  #pragma unroll
  for (int rr = 0; rr < 2; ++rr) inv_swz((tid + rr * 256) * 8, Rr[rr], Cr[rr]);

  f32x4 acc[4][4];
  #pragma unroll
  for (int mt = 0; mt < 4; ++mt)
    #pragma unroll
    for (int nt = 0; nt < 4; ++nt)
      acc[mt][nt] = (f32x4){0.f, 0.f, 0.f, 0.f};

  for (int k0 = 0; k0 < DM; k0 += 32) {
    #pragma unroll
    for (int rr = 0; rr < 2; ++rr) {
      const size_t goA = (size_t)(m0 + Rr[rr]) * DM + k0 + Cr[rr] * 8;
      const size_t goB = (size_t)(n0 + Rr[rr]) * DM + k0 + Cr[rr] * 8;
      const int lb = wid * 512 + rr * 2048;
      gl16(Xb + goA, As + lb);
      gl16(Wb + goB, Bs + lb);
    }
    __syncthreads();

    short8v af[4], bf[4];
    #pragma unroll
    for (int mt = 0; mt < 4; ++mt) {
      const int m = wr + mt * 16 + c;
      af[mt] = *reinterpret_cast<const short8v*>(As + ((m * 32 + G * 8) ^ ((m & 7) << 3)));
      const int n = wc + mt * 16 + c;
      bf[mt] = *reinterpret_cast<const short8v*>(Bs + ((n * 32 + G * 8) ^ ((n & 7) << 3)));
    }
    #pragma unroll
    for (int mt = 0; mt < 4; ++mt)
      #pragma unroll
      for (int nt = 0; nt < 4; ++nt)
        acc[mt][nt] = __builtin_amdgcn_mfma_f32_16x16x32_bf16(af[mt], bf[nt], acc[mt][nt], 0, 0, 0);
    __syncthreads();
  }

  float bb[4];
  #pragma unroll
  for (int nt = 0; nt < 4; ++nt) bb[nt] = bias[n0 + wc + nt * 16 + c];

  #pragma unroll
  for (int mt = 0; mt < 4; ++mt) {
    #pragma unroll
    for (int nt = 0; nt < 4; ++nt) {
      const int n = n0 + wc + nt * 16 + c;
      #pragma unroll
      for (int r = 0; r < 4; ++r) {
        const int m = m0 + wr + mt * 16 + G * 4 + r;
        Y[(size_t)m * DM + n] = acc[mt][nt][r] + bb[nt];
      }
    }
  }
}

// ---------------------------------------------------------------------------
// selectA: radix-select the 819th approx norm A; classify rows:
//   definite-in (> A(1+3b)) -> tix; uncertain (>= A(1-3b)) -> ukeys.
// (norms uniformly scaled by QSCALE^2 -- ordering & relative band invariant)
// ---------------------------------------------------------------------------
__global__ __launch_bounds__(1024) void selectA(
    const float* __restrict__ norms, int* __restrict__ tix,
    u64* __restrict__ ukeys, int* __restrict__ Dcnt, int* __restrict__ Ucnt)
{
  __shared__ unsigned int keys[LSEQ];
  __shared__ unsigned int hist[256];
  __shared__ unsigned int sh_b, sh_above;
  __shared__ unsigned int cD, cU;

  const int tid = threadIdx.x;
  const int bh = blockIdx.x;

  for (int l = tid; l < LSEQ; l += 1024)
    keys[l] = __float_as_uint(norms[bh * LSEQ + l]);
  if (tid == 0) { cD = 0; cU = 0; }
  __syncthreads();

  unsigned int prefix = 0, rem = TOPU;
  for (int shift = 24; shift >= 0; shift -= 8) {
    if (tid < 256) hist[tid] = 0;
    __syncthreads();
    for (int l = tid; l < LSEQ; l += 1024) {
      const unsigned int k = keys[l];
      const bool in = (shift == 24) || ((k >> (shift + 8)) == prefix);
      if (in) atomicAdd(&hist[(k >> shift) & 255], 1);
    }
    __syncthreads();
    if (tid == 0) {
      unsigned int cum = 0; int b = 255;
      for (; b > 0; --b) {
        const unsigned int h = hist[b];
        if (cum + h >= rem) break;
        cum += h;
      }
      sh_b = (unsigned int)b; sh_above = cum;
    }
    __syncthreads();
    prefix = (prefix << 8) | sh_b;
    rem -= sh_above;
    __syncthreads();
  }

  const float A = __uint_as_float(prefix);
  const float Whi = A * (1.0f + 3.0f * BAND);
  const float Wlo = A * (1.0f - 3.0f * BAND);

  for (int l = tid; l < LSEQ; l += 1024) {
    const float v = __uint_as_float(keys[l]);
    if (v > Whi) {
      const unsigned p = atomicAdd(&cD, 1);
      tix[bh * TOPU + p] = l;
    } else if (v >= Wlo) {
      const unsigned u = atomicAdd(&cU, 1);
      if (u < UCAP)
        ukeys[(size_t)bh * UCAP + u] =
            ((u64)keys[l] << 32) | (unsigned int)(~l);
    }
  }
  __syncthreads();
  if (tid == 0) {
    Dcnt[bh] = (int)cD;
    Ucnt[bh] = (int)(cU < UCAP ? cU : UCAP);
  }
}

// ---------------------------------------------------------------------------
// Recompute exact fp32 norms for uncertain rows -- ONE BLOCK PER ROW,
// lanes sweep k (coalesced W reads).
// ---------------------------------------------------------------------------
__global__ __launch_bounds__(256) void recompute_norms(
    const float* __restrict__ x, const float* __restrict__ Wq,
    const float* __restrict__ bq, u64* __restrict__ ukeys,
    const int* __restrict__ Ucnt)
{
  const int bh = blockIdx.x;
  const int r  = blockIdx.y;
  if (r >= Ucnt[bh]) return;

  __shared__ float xs[DM];       // 4 KB
  __shared__ float wsum[4];
  const int tid = threadIdx.x;
  const int wid = tid >> 6, lane = tid & 63;
  const int h = bh & 15, bI = bh >> 4;

  const u64 key = ukeys[(size_t)bh * UCAP + r];
  const int row = (int)(~(unsigned int)(key & 0xffffffffu));

  *reinterpret_cast<float4*>(xs + tid * 4) =
      *reinterpret_cast<const float4*>(
          x + (size_t)(bI * LSEQ + row) * DM + tid * 4);
  __syncthreads();

  float sq = 0.f;
  #pragma unroll 4
  for (int i = 0; i < 16; ++i) {
    const int d = wid * 16 + i;
    const float* wp = Wq + (size_t)(h * 64 + d) * DM;
    float s = 0.f;
    #pragma unroll
    for (int ch = 0; ch < 4; ++ch) {
      const float4 wv = *reinterpret_cast<const float4*>(wp + ch * 256 + lane * 4);
      const float4 xv = *reinterpret_cast<const float4*>(xs + ch * 256 + lane * 4);
      s = fmaf(wv.x, xv.x, s); s = fmaf(wv.y, xv.y, s);
      s = fmaf(wv.z, xv.z, s); s = fmaf(wv.w, xv.w, s);
    }
    s += __shfl_xor(s, 1);  s += __shfl_xor(s, 2);  s += __shfl_xor(s, 4);
    s += __shfl_xor(s, 8);  s += __shfl_xor(s, 16); s += __shfl_xor(s, 32);
    if (lane == 0) {
      const float q = s + bq[h * 64 + d];
      sq = fmaf(q, q, sq);
    }
  }
  if (lane == 0) wsum[wid] = sq;
  __syncthreads();
  if (tid == 0) {
    const float tot = wsum[0] + wsum[1] + wsum[2] + wsum[3];
    ukeys[(size_t)bh * UCAP + r] =
        ((u64)__float_as_uint(tot) << 32) | (key & 0xffffffffu);
  }
}

// ---------------------------------------------------------------------------
// selectB: bitonic sort (desc value, asc index) the uncertain keys (now with
// exact norms), append the top (819 - D) to tix.
// ---------------------------------------------------------------------------
__global__ __launch_bounds__(1024) void selectB(
    const u64* __restrict__ ukeys, const int* __restrict__ Dcnt,
    const int* __restrict__ Ucnt, int* __restrict__ tix)
{
  __shared__ u64 sk[UCAP];
  const int bh = blockIdx.x;
  const int U = Ucnt[bh], D = Dcnt[bh];
  const int need = TOPU - D;
  const int tid = threadIdx.x;

  sk[tid] = (tid < U) ? ukeys[(size_t)bh * UCAP + tid] : 0ULL;
  __syncthreads();
  for (int k = 2; k <= UCAP; k <<= 1) {
    for (int j = k >> 1; j > 0; j >>= 1) {
      const int ixj = tid ^ j;
      if (ixj > tid) {
        const bool desc = ((tid & k) == 0);
        const u64 a = sk[tid], b = sk[ixj];
        if (desc ? (a < b) : (a > b)) { sk[tid] = b; sk[ixj] = a; }
      }
      __syncthreads();
    }
  }
  if (tid < need)
    tix[bh * TOPU + D + tid] =
        (tid < U) ? (int)(~(unsigned int)(sk[tid] & 0xffffffffu)) : 0;
}

// ---------------------------------------------------------------------------
// MFMA flash attention, split-K x4, bf16 partial O + fp32 (m,lsum).
// Q pre-scaled by 0.125*log2e -> raw fragments, native exp2 softmax
// (m, lsum in log2 domain), cvt_pk P conversion, defer-max.
// ---------------------------------------------------------------------------
__global__ __launch_bounds__(256) void attn_mfma(
    const u16* __restrict__ Qbb, const u16* __restrict__ Kg,
    const u16* __restrict__ VgT, const int* __restrict__ tix,
    u16* __restrict__ OpartB, float* __restrict__ MLpart)
{
  __shared__ u16 Kc[128 * 64];
  __shared__ u16 Vt[64 * 128];
  __shared__ u16 Pt[4][16 * 136];

  const int tid = threadIdx.x;
  const int wid = tid >> 6, lane = tid & 63;
  const int c = lane & 15, G = lane >> 4;

  const int l = blockIdx.x;
  const int grp = l >> 3;                  // 0..207
  const int bh = (grp / 52) * 8 + (l & 7);
  const int rem = grp % 52;
  const int qb = rem >> 2, ks = rem & 3;

  const size_t bhL = (size_t)bh * LSEQ;
  const int rglob = qb * 64 + wid * 16 + c;
  const int rowidx = (rglob < TOPU) ? tix[bh * TOPU + rglob] : -1;

  short8v qf[2];
  #pragma unroll
  for (int kf = 0; kf < 2; ++kf) {
    if (rowidx >= 0) {
      qf[kf] = *reinterpret_cast<const short8v*>(
          Qbb + (bhL + rowidx) * HD + kf * 32 + G * 8);
    } else {
      short8v v;
      #pragma unroll
      for (int j = 0; j < 8; ++j) v[j] = 0;
      qf[kf] = v;
    }
  }

  float m = -1e30f, lsum = 0.f;
  f32x4 oacc[4];
  #pragma unroll
  for (int dt = 0; dt < 4; ++dt) oacc[dt] = (f32x4){0.f, 0.f, 0.f, 0.f};

  const int ko0 = ks * (LSEQ / NSEG);
  const int wbase = (tid & ~63) * 8;
  const int csw = c & 7;
  for (int t = 0; t < LSEQ / NSEG / 128; ++t) {
    const int ko = ko0 + t * 128;
    #pragma unroll
    for (int uu = 0; uu < 4; ++uu) {
      const int S = (uu * 256 + tid) * 8;
      const int key = S >> 6, dgk = ((S >> 3) & 7) ^ (key & 7);
      gl16(Kg + (bhL + ko + key) * HD + dgk * 8, Kc + uu * 2048 + wbase);
      const int d = S >> 7, kgv = ((S >> 3) & 15) ^ (d & 7);
      gl16(VgT + ((size_t)bh * HD + d) * LSEQ + ko + kgv * 8, Vt + uu * 2048 + wbase);
    }
    __syncthreads();

    f32x4 sacc[8];
    __builtin_amdgcn_s_setprio(1);
    #pragma unroll
    for (int kt = 0; kt < 8; ++kt) {
      const int key = kt * 16 + c;
      short8v kb0 = *reinterpret_cast<const short8v*>(
          Kc + key * 64 + (((0 + G) ^ (key & 7)) << 3));
      short8v kb1 = *reinterpret_cast<const short8v*>(
          Kc + key * 64 + (((4 + G) ^ (key & 7)) << 3));
      f32x4 s = (f32x4){0.f, 0.f, 0.f, 0.f};
      s = __builtin_amdgcn_mfma_f32_16x16x32_bf16(kb0, qf[0], s, 0, 0, 0);
      s = __builtin_amdgcn_mfma_f32_16x16x32_bf16(kb1, qf[1], s, 0, 0, 0);
      sacc[kt] = s;
    }
    __builtin_amdgcn_s_setprio(0);

    float smax = -1e30f;
    #pragma unroll
    for (int kt = 0; kt < 8; ++kt) {
      float a0 = fmaxf(sacc[kt][0], sacc[kt][1]);
      float a1 = fmaxf(sacc[kt][2], sacc[kt][3]);
      smax = fmaxf(smax, fmaxf(a0, a1));
    }
    smax = fmaxf(smax, __shfl_xor(smax, 16));
    smax = fmaxf(smax, __shfl_xor(smax, 32));

    // defer-max (T13): only rescale when some lane's max grew past THR=8
    if (!__all(smax - m <= 8.0f)) {
      const float mnew = fmaxf(m, smax);
      const float corr = fexp2(m - mnew);
      lsum *= corr;
      #pragma unroll
      for (int dt = 0; dt < 4; ++dt) oacc[dt] *= corr;
      m = mnew;
    }

    float ssum = 0.f;
    #pragma unroll
    for (int kt = 0; kt < 8; ++kt) {
      float p0 = fexp2(sacc[kt][0] - m);
      float p1 = fexp2(sacc[kt][1] - m);
      float p2 = fexp2(sacc[kt][2] - m);
      float p3 = fexp2(sacc[kt][3] - m);
      ssum += (p0 + p1) + (p2 + p3);
      unsigned pk01, pk23;
      asm("v_cvt_pk_bf16_f32 %0, %1, %2" : "=v"(pk01) : "v"(p0), "v"(p1));
      asm("v_cvt_pk_bf16_f32 %0, %1, %2" : "=v"(pk23) : "v"(p2), "v"(p3));
      uint2 pv; pv.x = pk01; pv.y = pk23;
      *reinterpret_cast<uint2*>(
          &Pt[wid][c * 136 + ((kt ^ csw) << 4) + G * 4]) = pv;
    }
    ssum += __shfl_xor(ssum, 16);
    ssum += __shfl_xor(ssum, 32);
    lsum += ssum;

    __builtin_amdgcn_s_setprio(1);
    #pragma unroll
    for (int kf = 0; kf < 4; ++kf) {
      short8v pf = *reinterpret_cast<const short8v*>(
          &Pt[wid][c * 136 + (((2 * kf + (G >> 1)) ^ csw) << 4) + (G & 1) * 8]);
      #pragma unroll
      for (int dt = 0; dt < 4; ++dt) {
        const int d = dt * 16 + c;
        short8v vf = *reinterpret_cast<const short8v*>(
            Vt + d * 128 + (((kf * 4 + G) ^ (d & 7)) << 3));
        oacc[dt] = __builtin_amdgcn_mfma_f32_16x16x32_bf16(vf, pf, oacc[dt], 0, 0, 0);
      }
    }
    __builtin_amdgcn_s_setprio(0);
    __syncthreads();
  }

  const int q = wid * 16 + c;
  const size_t pb = ((size_t)((bh * 13 + qb) * NSEG + ks)) * 64 + q;
  u16* op = OpartB + pb * 64;
  #pragma unroll
  for (int dt = 0; dt < 4; ++dt) {
    short4v o;
    o[0] = (short)f2bf(oacc[dt][0]); o[1] = (short)f2bf(oacc[dt][1]);
    o[2] = (short)f2bf(oacc[dt][2]); o[3] = (short)f2bf(oacc[dt][3]);
    *reinterpret_cast<short4v*>(op + dt * 16 + G * 4) = o;
  }
  if (G == 0) {
    MLpart[pb * 2]     = m;     // log2-domain running max
    MLpart[pb * 2 + 1] = lsum;
  }
}

// ---------------------------------------------------------------------------
// 4-way split-K combine (log2-domain m): O = sum Oi*ci / sum li*ci, bf16 out.
// ---------------------------------------------------------------------------
__global__ __launch_bounds__(256) void attn_combine(
    const u16* __restrict__ OpartB, const float* __restrict__ MLpart,
    const int* __restrict__ tix, u16* __restrict__ O1b)
{
  const int bq = blockIdx.x;
  const int bh = bq / 13, qb = bq % 13;
  const int tid = threadIdx.x;
  const int q = tid >> 2, dq = (tid & 3) * 16;
  const int rglob = qb * 64 + q;
  if (rglob >= TOPU) return;
  const int rowidx = tix[bh * TOPU + rglob];

  size_t p[NSEG];
  float mi[NSEG], li[NSEG];
  #pragma unroll
  for (int i = 0; i < NSEG; ++i) {
    p[i] = ((size_t)bq * NSEG + i) * 64 + q;
    mi[i] = MLpart[p[i] * 2];
    li[i] = MLpart[p[i] * 2 + 1];
  }
  float mx = fmaxf(fmaxf(mi[0], mi[1]), fmaxf(mi[2], mi[3]));
  float ci[NSEG], lsum = 0.f;
  #pragma unroll
  for (int i = 0; i < NSEG; ++i) { ci[i] = fexp2(mi[i] - mx); lsum += li[i] * ci[i]; }
  const float linv = 1.0f / lsum;

  float acc[16];
  #pragma unroll
  for (int j = 0; j < 16; ++j) acc[j] = 0.f;
  #pragma unroll
  for (int i = 0; i < NSEG; ++i) {
    const u16* src = OpartB + p[i] * 64 + dq;
    #pragma unroll
    for (int j = 0; j < 16; ++j) acc[j] += bf2f(src[j]) * ci[i];
  }

  const int b = bh >> 4, h = bh & 15;
  u16* dst = O1b + (size_t)(b * LSEQ + rowidx) * DM + h * HD + dq;
  #pragma unroll
  for (int j0 = 0; j0 < 16; j0 += 4) {
    short4v o;
    #pragma unroll
    for (int j = 0; j < 4; ++j) o[j] = (short)f2bf(acc[j0 + j] * linv);
    *reinterpret_cast<short4v*>(dst + j0) = o;
  }
}

// ---------------------------------------------------------------------------
extern "C" void kernel_launch(void* const* d_in, const int* in_sizes, int n_in,
                              void* d_out, int out_size, void* d_ws, size_t ws_size,
                              hipStream_t stream) {
  const float* x  = (const float*)d_in[0];
  const float* Wq = (const float*)d_in[1];
  const float* bq = (const float*)d_in[2];
  const float* Wk = (const float*)d_in[3];
  const float* bk = (const float*)d_in[4];
  const float* Wv = (const float*)d_in[5];
  const float* bv = (const float*)d_in[6];
  const float* Wo = (const float*)d_in[7];
  const float* bo = (const float*)d_in[8];
  float* out = (float*)d_out;

  char* w = (char*)d_ws;
  u16* xb   = (u16*)w;  w += (size_t)MROWS * DM * 2;           // 16 MB -> OpartB/ML
  u16* Qbb  = (u16*)w;  w += (size_t)BHT * LSEQ * HD * 2;      // 16 MB
  u16* Kb   = (u16*)w;  w += (size_t)BHT * LSEQ * HD * 2;      // 16 MB
  u16* VgT  = (u16*)w;  w += (size_t)BHT * HD * LSEQ * 2;      // 16 MB
  u16* O1b  = (u16*)w;  w += (size_t)MROWS * DM * 2;           // 16 MB
  u16* Wqb  = (u16*)w;  w += (size_t)DM * DM * 2;              // 2 MB
  u16* Wkb  = (u16*)w;  w += (size_t)DM * DM * 2;
  u16* Wvb  = (u16*)w;  w += (size_t)DM * DM * 2;
  u16* Wob  = (u16*)w;  w += (size_t)DM * DM * 2;
  float* norms = (float*)w; w += (size_t)BHT * LSEQ * 4;       // 512 KB
  int* tix  = (int*)w;  w += (size_t)BHT * TOPU * 4;           // 105 KB
  u64* ukeys = (u64*)w; w += (size_t)BHT * UCAP * 8;           // 256 KB
  int* Dcnt = (int*)w;  w += 128;
  int* Ucnt = (int*)w;  w += 128;

  // attn partials alias xb (dead after gemm_proj): 13.6 + 0.85 MB <= 16 MB
  u16*   OpartB = xb;
  const int NPB = BHT * 13 * NSEG * 64;
  float* MLpart = (float*)(OpartB + (size_t)NPB * 64);

  prep_all<<<6144, 256, 0, stream>>>(x, Wq, Wk, Wv, Wo, xb, Wqb, Wkb, Wvb, Wob);

  gemm_proj<<<dim3(64, 24), 256, 0, stream>>>(
      xb, Wqb, Wkb, Wvb, bq, bk, bv, Qbb, norms, Kb, VgT);

  selectA<<<BHT, 1024, 0, stream>>>(norms, tix, ukeys, Dcnt, Ucnt);
  recompute_norms<<<dim3(BHT, UCAP), 256, 0, stream>>>(x, Wq, bq, ukeys, Ucnt);
  selectB<<<BHT, 1024, 0, stream>>>(ukeys, Dcnt, Ucnt, tix);

  hipMemsetAsync(O1b, 0, (size_t)MROWS * DM * 2, stream);

  attn_mfma<<<BHT * 13 * NSEG, 256, 0, stream>>>(Qbb, Kb, VgT, tix, OpartB, MLpart);
  attn_combine<<<BHT * 13, 256, 0, stream>>>(OpartB, MLpart, tix, O1b);

  gemm_out<<<dim3(MROWS / 128, DM / 128), 256, 0, stream>>>(O1b, Wob, bo, out);
}

// Round 18
// 258.070 us; speedup vs baseline: 1.0306x; 1.0061x over previous
//
#include <hip/hip_runtime.h>
#include <cstddef>
#include <cstdint>

constexpr int LSEQ = 4096;
constexpr int DM   = 1024;
constexpr int HD   = 64;
constexpr int BHT  = 32;     // B*H
constexpr int TOPU = 819;
constexpr int MROWS = 8192;  // B*L
constexpr int NSEG = 4;      // attention split-K segments
constexpr int UCAP = 1024;   // uncertain-row capacity per bh
#define BAND 2.4e-3f         // 6-sigma bound on approx-norm relative error
#define QSCALE 0.180336880f  // 0.125 * log2(e): softmax scale in log2 domain

typedef unsigned short u16;
typedef unsigned long long u64;
typedef __attribute__((ext_vector_type(8))) short short8v;  // 8 bf16
typedef __attribute__((ext_vector_type(4))) short short4v;  // 4 bf16
typedef __attribute__((ext_vector_type(4))) float f32x4;

__device__ __forceinline__ u16 f2bf(float f) {
  uint32_t u = __float_as_uint(f);
  u += 0x7fffu + ((u >> 16) & 1u);   // RNE
  return (u16)(u >> 16);
}
__device__ __forceinline__ float bf2f(u16 h) {
  return __uint_as_float(((uint32_t)h) << 16);
}
// native 2^x (v_exp_f32 IS exp2)
__device__ __forceinline__ float fexp2(float x) {
  float r; asm("v_exp_f32 %0, %1" : "=v"(r) : "v"(x)); return r;
}

// async 16B global -> LDS (DMA).  LDS dest wave-uniform base; HW adds lane*16.
__device__ __forceinline__ void gl16(const void* g, void* l) {
  __builtin_amdgcn_global_load_lds(
      (const __attribute__((address_space(1))) void*)g,
      (__attribute__((address_space(3))) void*)l, 16, 0, 0);
}

// Inverse of the LDS swizzle e = (R*32 + C*8) ^ ((R&7)<<3) for linear slot S.
__device__ __forceinline__ void inv_swz(int S, int& R, int& C) {
  const int R0 = ((S >> 5) ^ (S >> 7)) & 1;
  const int R1 = (S >> 6) & 1;
  R = ((S >> 6) << 1) | R0;
  C = (((S >> 3) & 1) ^ R0) | ((((S >> 4) & 1) ^ R1) << 1);
}

// ---------------------------------------------------------------------------
// Prep: bf16 conversions (x, Wq*QSCALE, Wk, Wv, Wo).
// ---------------------------------------------------------------------------
__device__ __forceinline__ void conv_body(const float* src, u16* dst, int i,
                                          float sc) {
  const float4 a = *reinterpret_cast<const float4*>(src + (size_t)i * 8);
  const float4 b = *reinterpret_cast<const float4*>(src + (size_t)i * 8 + 4);
  short8v v;
  v[0] = (short)f2bf(a.x * sc); v[1] = (short)f2bf(a.y * sc);
  v[2] = (short)f2bf(a.z * sc); v[3] = (short)f2bf(a.w * sc);
  v[4] = (short)f2bf(b.x * sc); v[5] = (short)f2bf(b.y * sc);
  v[6] = (short)f2bf(b.z * sc); v[7] = (short)f2bf(b.w * sc);
  *reinterpret_cast<short8v*>(dst + (size_t)i * 8) = v;
}

__global__ __launch_bounds__(256) void prep_all(
    const float* __restrict__ x,  const float* __restrict__ Wq,
    const float* __restrict__ Wk, const float* __restrict__ Wv,
    const float* __restrict__ Wo,
    u16* __restrict__ xb, u16* __restrict__ Wqb, u16* __restrict__ Wkb,
    u16* __restrict__ Wvb, u16* __restrict__ Wob)
{
  const int NX = MROWS * DM / 8;   // 1048576
  const int NW = DM * DM / 8;      // 131072
  int i = blockIdx.x * 256 + threadIdx.x;
  if (i < NX)  { conv_body(x,  xb,  i, 1.0f); return; }
  i -= NX;
  if (i < NW)  { conv_body(Wq, Wqb, i, QSCALE); return; }
  i -= NW;
  if (i < NW)  { conv_body(Wk, Wkb, i, 1.0f); return; }
  i -= NW;
  if (i < NW)  { conv_body(Wv, Wvb, i, 1.0f); return; }
  i -= NW;
  if (i < NW)  { conv_body(Wo, Wob, i, 1.0f); }
}

// ---------------------------------------------------------------------------
// Single-product projection body, split-head bf16 out; optional fused norms.
// ---------------------------------------------------------------------------
template<bool SCALEB>
__device__ __forceinline__ void proj_sh_body(
    u16* smem, const u16* __restrict__ Xb, const u16* __restrict__ Wb,
    const float* __restrict__ bias, u16* __restrict__ dst,
    float* __restrict__ norms, int bx, int ny)
{
  u16* As = smem;
  u16* Bs = smem + 4096;
  const int tid = threadIdx.x;
  const int m0 = bx * 128, n0 = ny * 128;
  const int wid = tid >> 6, lane = tid & 63;
  const int wr = (wid >> 1) * 64, wc = (wid & 1) * 64;
  const int c = lane & 15, G = lane >> 4;

  int Rr[2], Cr[2];
  #pragma unroll
  for (int rr = 0; rr < 2; ++rr) inv_swz((tid + rr * 256) * 8, Rr[rr], Cr[rr]);

  f32x4 acc[4][4];
  #pragma unroll
  for (int mt = 0; mt < 4; ++mt)
    #pragma unroll
    for (int nt = 0; nt < 4; ++nt)
      acc[mt][nt] = (f32x4){0.f, 0.f, 0.f, 0.f};

  for (int k0 = 0; k0 < DM; k0 += 32) {
    #pragma unroll
    for (int rr = 0; rr < 2; ++rr) {
      const size_t goA = (size_t)(m0 + Rr[rr]) * DM + k0 + Cr[rr] * 8;
      const size_t goB = (size_t)(n0 + Rr[rr]) * DM + k0 + Cr[rr] * 8;
      const int lb = wid * 512 + rr * 2048;
      gl16(Xb + goA, As + lb);
      gl16(Wb + goB, Bs + lb);
    }
    __syncthreads();

    short8v af[4], bf[4];
    #pragma unroll
    for (int mt = 0; mt < 4; ++mt) {
      const int m = wr + mt * 16 + c;
      af[mt] = *reinterpret_cast<const short8v*>(As + ((m * 32 + G * 8) ^ ((m & 7) << 3)));
      const int n = wc + mt * 16 + c;
      bf[mt] = *reinterpret_cast<const short8v*>(Bs + ((n * 32 + G * 8) ^ ((n & 7) << 3)));
    }
    #pragma unroll
    for (int mt = 0; mt < 4; ++mt)
      #pragma unroll
      for (int nt = 0; nt < 4; ++nt)
        acc[mt][nt] = __builtin_amdgcn_mfma_f32_16x16x32_bf16(af[mt], bf[nt], acc[mt][nt], 0, 0, 0);
    __syncthreads();
  }

  float bb[4];
  #pragma unroll
  for (int nt = 0; nt < 4; ++nt) {
    bb[nt] = bias[n0 + wc + nt * 16 + c];
    if (SCALEB) bb[nt] *= QSCALE;
  }

  float ns[4][4];
  #pragma unroll
  for (int mt = 0; mt < 4; ++mt)
    #pragma unroll
    for (int r = 0; r < 4; ++r) ns[mt][r] = 0.f;

  #pragma unroll
  for (int mt = 0; mt < 4; ++mt) {
    #pragma unroll
    for (int nt = 0; nt < 4; ++nt) {
      const int n = n0 + wc + nt * 16 + c;
      const int h = n >> 6, d = n & 63;
      #pragma unroll
      for (int r = 0; r < 4; ++r) {
        const int m = m0 + wr + mt * 16 + G * 4 + r;
        const int b = m >> 12, l = m & (LSEQ - 1);
        const float val = acc[mt][nt][r] + bb[nt];
        dst[((size_t)((b << 4) + h) * LSEQ + l) * HD + d] = f2bf(val);
        ns[mt][r] = fmaf(val, val, ns[mt][r]);
      }
    }
  }
  if (norms) {
    #pragma unroll
    for (int mt = 0; mt < 4; ++mt)
      #pragma unroll
      for (int r = 0; r < 4; ++r) {
        float v = ns[mt][r];
        v += __shfl_xor(v, 1); v += __shfl_xor(v, 2);
        v += __shfl_xor(v, 4); v += __shfl_xor(v, 8);
        ns[mt][r] = v;
      }
    if (c == 0) {
      const int h = (n0 + wc) >> 6;
      #pragma unroll
      for (int mt = 0; mt < 4; ++mt)
        #pragma unroll
        for (int r = 0; r < 4; ++r) {
          const int m = m0 + wr + mt * 16 + G * 4 + r;
          const int b = m >> 12, l = m & (LSEQ - 1);
          norms[(((size_t)((b << 4) + h)) << 12) + l] = ns[mt][r];
        }
    }
  }
}

// ---------------------------------------------------------------------------
// V projection body: transposed per-head out [bh*64+d][4096] via LDS T.
// ---------------------------------------------------------------------------
__device__ __forceinline__ void proj_v_body(
    u16* smem, const u16* __restrict__ Xb, const u16* __restrict__ Wb,
    const float* __restrict__ bias, u16* __restrict__ VgT, int bx, int ny)
{
  u16* As = smem;
  u16* Bs = smem + 4096;
  const int tid = threadIdx.x;
  const int m0 = bx * 128, n0 = ny * 128;
  const int wid = tid >> 6, lane = tid & 63;
  const int wr = (wid >> 1) * 64, wc = (wid & 1) * 64;
  const int c = lane & 15, G = lane >> 4;

  int Rr[2], Cr[2];
  #pragma unroll
  for (int rr = 0; rr < 2; ++rr) inv_swz((tid + rr * 256) * 8, Rr[rr], Cr[rr]);

  f32x4 acc[4][4];
  #pragma unroll
  for (int mt = 0; mt < 4; ++mt)
    #pragma unroll
    for (int nt = 0; nt < 4; ++nt)
      acc[mt][nt] = (f32x4){0.f, 0.f, 0.f, 0.f};

  for (int k0 = 0; k0 < DM; k0 += 32) {
    #pragma unroll
    for (int rr = 0; rr < 2; ++rr) {
      const size_t goA = (size_t)(m0 + Rr[rr]) * DM + k0 + Cr[rr] * 8;
      const size_t goB = (size_t)(n0 + Rr[rr]) * DM + k0 + Cr[rr] * 8;
      const int lb = wid * 512 + rr * 2048;
      gl16(Xb + goA, As + lb);
      gl16(Wb + goB, Bs + lb);
    }
    __syncthreads();

    short8v af[4], bf[4];
    #pragma unroll
    for (int mt = 0; mt < 4; ++mt) {
      const int m = wr + mt * 16 + c;
      af[mt] = *reinterpret_cast<const short8v*>(As + ((m * 32 + G * 8) ^ ((m & 7) << 3)));
      const int n = wc + mt * 16 + c;
      bf[mt] = *reinterpret_cast<const short8v*>(Bs + ((n * 32 + G * 8) ^ ((n & 7) << 3)));
    }
    #pragma unroll
    for (int mt = 0; mt < 4; ++mt)
      #pragma unroll
      for (int nt = 0; nt < 4; ++nt)
        acc[mt][nt] = __builtin_amdgcn_mfma_f32_16x16x32_bf16(af[mt], bf[nt], acc[mt][nt], 0, 0, 0);
    __syncthreads();
  }

  float bb[4];
  #pragma unroll
  for (int nt = 0; nt < 4; ++nt) bb[nt] = bias[n0 + wc + nt * 16 + c];

  #pragma unroll
  for (int mt = 0; mt < 4; ++mt) {
    #pragma unroll
    for (int nt = 0; nt < 4; ++nt) {
      const int n = wc + nt * 16 + c;
      const int mloc = wr + mt * 16 + G * 4;
      short4v pv;
      #pragma unroll
      for (int r = 0; r < 4; ++r) pv[r] = (short)f2bf(acc[mt][nt][r] + bb[nt]);
      *reinterpret_cast<short4v*>(smem + n * 136 + mloc) = pv;
    }
  }
  __syncthreads();
  const int bb2 = m0 >> 12;
  const int ml0 = m0 & (LSEQ - 1);
  #pragma unroll
  for (int uu = 0; uu < 8; ++uu) {
    const int u = uu * 256 + tid;
    const int n = u >> 4, kg = u & 15;
    short8v vvv = *reinterpret_cast<const short8v*>(smem + n * 136 + kg * 8);
    const int h = (n0 + n) >> 6, d = (n0 + n) & 63;
    *reinterpret_cast<short8v*>(
        VgT + ((size_t)((bb2 << 4) + h) * HD + d) * LSEQ + ml0 + kg * 8) = vvv;
  }
}

// ---------------------------------------------------------------------------
// Fused projection: by < 8 -> Q; 8..15 -> V; >=16 -> K.
// ---------------------------------------------------------------------------
__global__ __launch_bounds__(256) void gemm_proj(
    const u16* __restrict__ Xb,
    const u16* __restrict__ Wqb, const u16* __restrict__ Wkb, const u16* __restrict__ Wvb,
    const float* __restrict__ bq, const float* __restrict__ bk, const float* __restrict__ bv,
    u16* __restrict__ Qbb, float* __restrict__ norms,
    u16* __restrict__ Kb, u16* __restrict__ VgT)
{
  __shared__ __align__(16) u16 smem[17408];   // 34816 B union
  const int by = blockIdx.y;
  const int bx = blockIdx.x;
  if (by < 8) {
    proj_sh_body<true>(smem, Xb, Wqb, bq, Qbb, norms, bx, by);
  } else if (by < 16) {
    proj_v_body(smem, Xb, Wvb, bv, VgT, bx, by - 8);
  } else {
    proj_sh_body<false>(smem, Xb, Wkb, bk, Kb, nullptr, bx, by - 16);
  }
}

// ---------------------------------------------------------------------------
// Output GEMM: out = O1b(bf16) @ Wob^T + bo, fp32 row-major out.
// ---------------------------------------------------------------------------
__global__ __launch_bounds__(256) void gemm_out(
    const u16* __restrict__ Xb, const u16* __restrict__ Wb,
    const float* __restrict__ bias, float* __restrict__ Y)
{
  __shared__ u16 As[128 * 32];
  __shared__ u16 Bs[128 * 32];
  const int tid = threadIdx.x;
  const int m0 = blockIdx.x * 128, n0 = blockIdx.y * 128;
  const int wid = tid >> 6, lane = tid & 63;
  const int wr = (wid >> 1) * 64, wc = (wid & 1) * 64;
  const int c = lane & 15, G = lane >> 4;

  int Rr[2], Cr[2];
  #pragma unroll
  for (int rr = 0; rr < 2; ++rr) inv_swz((tid + rr * 256) * 8, Rr[rr], Cr[rr]);

  f32x4 acc[4][4];
  #pragma unroll
  for (int mt = 0; mt < 4; ++mt)
    #pragma unroll
    for (int nt = 0; nt < 4; ++nt)
      acc[mt][nt] = (f32x4){0.f, 0.f, 0.f, 0.f};

  for (int k0 = 0; k0 < DM; k0 += 32) {
    #pragma unroll
    for (int rr = 0; rr < 2; ++rr) {
      const size_t goA = (size_t)(m0 + Rr[rr]) * DM + k0 + Cr[rr] * 8;
      const size_t goB = (size_t)(n0 + Rr[rr]) * DM + k0 + Cr[rr] * 8;
      const int lb = wid * 512 + rr * 2048;
      gl16(Xb + goA, As + lb);
      gl16(Wb + goB, Bs + lb);
    }
    __syncthreads();

    short8v af[4], bf[4];
    #pragma unroll
    for (int mt = 0; mt < 4; ++mt) {
      const int m = wr + mt * 16 + c;
      af[mt] = *reinterpret_cast<const short8v*>(As + ((m * 32 + G * 8) ^ ((m & 7) << 3)));
      const int n = wc + mt * 16 + c;
      bf[mt] = *reinterpret_cast<const short8v*>(Bs + ((n * 32 + G * 8) ^ ((n & 7) << 3)));
    }
    #pragma unroll
    for (int mt = 0; mt < 4; ++mt)
      #pragma unroll
      for (int nt = 0; nt < 4; ++nt)
        acc[mt][nt] = __builtin_amdgcn_mfma_f32_16x16x32_bf16(af[mt], bf[nt], acc[mt][nt], 0, 0, 0);
    __syncthreads();
  }

  float bb[4];
  #pragma unroll
  for (int nt = 0; nt < 4; ++nt) bb[nt] = bias[n0 + wc + nt * 16 + c];

  #pragma unroll
  for (int mt = 0; mt < 4; ++mt) {
    #pragma unroll
    for (int nt = 0; nt < 4; ++nt) {
      const int n = n0 + wc + nt * 16 + c;
      #pragma unroll
      for (int r = 0; r < 4; ++r) {
        const int m = m0 + wr + mt * 16 + G * 4 + r;
        Y[(size_t)m * DM + n] = acc[mt][nt][r] + bb[nt];
      }
    }
  }
}

// ---------------------------------------------------------------------------
// selectA: radix-select the 819th approx norm A; classify rows.
// ---------------------------------------------------------------------------
__global__ __launch_bounds__(1024) void selectA(
    const float* __restrict__ norms, int* __restrict__ tix,
    u64* __restrict__ ukeys, int* __restrict__ Dcnt, int* __restrict__ Ucnt)
{
  __shared__ unsigned int keys[LSEQ];
  __shared__ unsigned int hist[256];
  __shared__ unsigned int sh_b, sh_above;
  __shared__ unsigned int cD, cU;

  const int tid = threadIdx.x;
  const int bh = blockIdx.x;

  for (int l = tid; l < LSEQ; l += 1024)
    keys[l] = __float_as_uint(norms[bh * LSEQ + l]);
  if (tid == 0) { cD = 0; cU = 0; }
  __syncthreads();

  unsigned int prefix = 0, rem = TOPU;
  for (int shift = 24; shift >= 0; shift -= 8) {
    if (tid < 256) hist[tid] = 0;
    __syncthreads();
    for (int l = tid; l < LSEQ; l += 1024) {
      const unsigned int k = keys[l];
      const bool in = (shift == 24) || ((k >> (shift + 8)) == prefix);
      if (in) atomicAdd(&hist[(k >> shift) & 255], 1);
    }
    __syncthreads();
    if (tid == 0) {
      unsigned int cum = 0; int b = 255;
      for (; b > 0; --b) {
        const unsigned int h = hist[b];
        if (cum + h >= rem) break;
        cum += h;
      }
      sh_b = (unsigned int)b; sh_above = cum;
    }
    __syncthreads();
    prefix = (prefix << 8) | sh_b;
    rem -= sh_above;
    __syncthreads();
  }

  const float A = __uint_as_float(prefix);
  const float Whi = A * (1.0f + 3.0f * BAND);
  const float Wlo = A * (1.0f - 3.0f * BAND);

  for (int l = tid; l < LSEQ; l += 1024) {
    const float v = __uint_as_float(keys[l]);
    if (v > Whi) {
      const unsigned p = atomicAdd(&cD, 1);
      tix[bh * TOPU + p] = l;
    } else if (v >= Wlo) {
      const unsigned u = atomicAdd(&cU, 1);
      if (u < UCAP)
        ukeys[(size_t)bh * UCAP + u] =
            ((u64)keys[l] << 32) | (unsigned int)(~l);
    }
  }
  __syncthreads();
  if (tid == 0) {
    Dcnt[bh] = (int)cD;
    Ucnt[bh] = (int)(cU < UCAP ? cU : UCAP);
  }
}

// ---------------------------------------------------------------------------
// Recompute exact fp32 norms for uncertain rows -- ONE BLOCK PER ROW,
// lanes sweep k (coalesced W reads).
// ---------------------------------------------------------------------------
__global__ __launch_bounds__(256) void recompute_norms(
    const float* __restrict__ x, const float* __restrict__ Wq,
    const float* __restrict__ bq, u64* __restrict__ ukeys,
    const int* __restrict__ Ucnt)
{
  const int bh = blockIdx.x;
  const int r  = blockIdx.y;
  if (r >= Ucnt[bh]) return;

  __shared__ float xs[DM];       // 4 KB
  __shared__ float wsum[4];
  const int tid = threadIdx.x;
  const int wid = tid >> 6, lane = tid & 63;
  const int h = bh & 15, bI = bh >> 4;

  const u64 key = ukeys[(size_t)bh * UCAP + r];
  const int row = (int)(~(unsigned int)(key & 0xffffffffu));

  *reinterpret_cast<float4*>(xs + tid * 4) =
      *reinterpret_cast<const float4*>(
          x + (size_t)(bI * LSEQ + row) * DM + tid * 4);
  __syncthreads();

  float sq = 0.f;
  #pragma unroll 4
  for (int i = 0; i < 16; ++i) {
    const int d = wid * 16 + i;
    const float* wp = Wq + (size_t)(h * 64 + d) * DM;
    float s = 0.f;
    #pragma unroll
    for (int ch = 0; ch < 4; ++ch) {
      const float4 wv = *reinterpret_cast<const float4*>(wp + ch * 256 + lane * 4);
      const float4 xv = *reinterpret_cast<const float4*>(xs + ch * 256 + lane * 4);
      s = fmaf(wv.x, xv.x, s); s = fmaf(wv.y, xv.y, s);
      s = fmaf(wv.z, xv.z, s); s = fmaf(wv.w, xv.w, s);
    }
    s += __shfl_xor(s, 1);  s += __shfl_xor(s, 2);  s += __shfl_xor(s, 4);
    s += __shfl_xor(s, 8);  s += __shfl_xor(s, 16); s += __shfl_xor(s, 32);
    if (lane == 0) {
      const float q = s + bq[h * 64 + d];
      sq = fmaf(q, q, sq);
    }
  }
  if (lane == 0) wsum[wid] = sq;
  __syncthreads();
  if (tid == 0) {
    const float tot = wsum[0] + wsum[1] + wsum[2] + wsum[3];
    ukeys[(size_t)bh * UCAP + r] =
        ((u64)__float_as_uint(tot) << 32) | (key & 0xffffffffu);
  }
}

// ---------------------------------------------------------------------------
// selectB: bitonic sort (desc value, asc index) the uncertain keys,
// append the top (819 - D) to tix.
// ---------------------------------------------------------------------------
__global__ __launch_bounds__(1024) void selectB(
    const u64* __restrict__ ukeys, const int* __restrict__ Dcnt,
    const int* __restrict__ Ucnt, int* __restrict__ tix)
{
  __shared__ u64 sk[UCAP];
  const int bh = blockIdx.x;
  const int U = Ucnt[bh], D = Dcnt[bh];
  const int need = TOPU - D;
  const int tid = threadIdx.x;

  sk[tid] = (tid < U) ? ukeys[(size_t)bh * UCAP + tid] : 0ULL;
  __syncthreads();
  for (int k = 2; k <= UCAP; k <<= 1) {
    for (int j = k >> 1; j > 0; j >>= 1) {
      const int ixj = tid ^ j;
      if (ixj > tid) {
        const bool desc = ((tid & k) == 0);
        const u64 a = sk[tid], b = sk[ixj];
        if (desc ? (a < b) : (a > b)) { sk[tid] = b; sk[ixj] = a; }
      }
      __syncthreads();
    }
  }
  if (tid < need)
    tix[bh * TOPU + D + tid] =
        (tid < U) ? (int)(~(unsigned int)(sk[tid] & 0xffffffffu)) : 0;
}

// ---------------------------------------------------------------------------
// MFMA flash attention, split-K x4, KVBLK=64 (25.6 KB LDS -> 6 blocks/CU).
// Q pre-scaled by 0.125*log2e -> raw fragments, native exp2 softmax
// (m, lsum in log2 domain), cvt_pk P conversion, defer-max.
// ---------------------------------------------------------------------------
__global__ __launch_bounds__(256) void attn_mfma(
    const u16* __restrict__ Qbb, const u16* __restrict__ Kg,
    const u16* __restrict__ VgT, const int* __restrict__ tix,
    u16* __restrict__ OpartB, float* __restrict__ MLpart)
{
  __shared__ u16 Kc[64 * 64];       // 8 KB  [key][d-granule ^ (key&7)]
  __shared__ u16 Vt[64 * 64];       // 8 KB  [d][k-granule ^ (d&7)]
  __shared__ u16 Pt[4][16 * 72];    // 9.2 KB per-wave [q][k], 4 chunks of 16

  const int tid = threadIdx.x;
  const int wid = tid >> 6, lane = tid & 63;
  const int c = lane & 15, G = lane >> 4;

  const int l = blockIdx.x;
  const int grp = l >> 3;                  // 0..207
  const int bh = (grp / 52) * 8 + (l & 7);
  const int rem = grp % 52;
  const int qb = rem >> 2, ks = rem & 3;

  const size_t bhL = (size_t)bh * LSEQ;
  const int rglob = qb * 64 + wid * 16 + c;
  const int rowidx = (rglob < TOPU) ? tix[bh * TOPU + rglob] : -1;

  short8v qf[2];
  #pragma unroll
  for (int kf = 0; kf < 2; ++kf) {
    if (rowidx >= 0) {
      qf[kf] = *reinterpret_cast<const short8v*>(
          Qbb + (bhL + rowidx) * HD + kf * 32 + G * 8);
    } else {
      short8v v;
      #pragma unroll
      for (int j = 0; j < 8; ++j) v[j] = 0;
      qf[kf] = v;
    }
  }

  float m = -1e30f, lsum = 0.f;
  f32x4 oacc[4];
  #pragma unroll
  for (int dt = 0; dt < 4; ++dt) oacc[dt] = (f32x4){0.f, 0.f, 0.f, 0.f};

  const int ko0 = ks * (LSEQ / NSEG);
  const int wbase = (tid & ~63) * 8;       // wave-uniform LDS slot base (u16)
  const int csw = c & 3;                   // Pt 4-chunk swizzle key
  for (int t = 0; t < LSEQ / NSEG / 64; ++t) {
    const int ko = ko0 + t * 64;
    #pragma unroll
    for (int uu = 0; uu < 2; ++uu) {
      const int S = (uu * 256 + tid) * 8;      // 0..4095 u16
      const int key = S >> 6, dgk = ((S >> 3) & 7) ^ (key & 7);
      gl16(Kg + (bhL + ko + key) * HD + dgk * 8, Kc + uu * 2048 + wbase);
      const int d = S >> 6, kgv = ((S >> 3) & 7) ^ (d & 7);
      gl16(VgT + ((size_t)bh * HD + d) * LSEQ + ko + kgv * 8, Vt + uu * 2048 + wbase);
    }
    __syncthreads();

    f32x4 sacc[4];
    __builtin_amdgcn_s_setprio(1);
    #pragma unroll
    for (int kt = 0; kt < 4; ++kt) {
      const int key = kt * 16 + c;
      short8v kb0 = *reinterpret_cast<const short8v*>(
          Kc + key * 64 + (((0 + G) ^ (key & 7)) << 3));
      short8v kb1 = *reinterpret_cast<const short8v*>(
          Kc + key * 64 + (((4 + G) ^ (key & 7)) << 3));
      f32x4 s = (f32x4){0.f, 0.f, 0.f, 0.f};
      s = __builtin_amdgcn_mfma_f32_16x16x32_bf16(kb0, qf[0], s, 0, 0, 0);
      s = __builtin_amdgcn_mfma_f32_16x16x32_bf16(kb1, qf[1], s, 0, 0, 0);
      sacc[kt] = s;
    }
    __builtin_amdgcn_s_setprio(0);

    float smax = -1e30f;
    #pragma unroll
    for (int kt = 0; kt < 4; ++kt) {
      float a0 = fmaxf(sacc[kt][0], sacc[kt][1]);
      float a1 = fmaxf(sacc[kt][2], sacc[kt][3]);
      smax = fmaxf(smax, fmaxf(a0, a1));
    }
    smax = fmaxf(smax, __shfl_xor(smax, 16));
    smax = fmaxf(smax, __shfl_xor(smax, 32));

    // defer-max (T13): only rescale when some lane's max grew past THR=8
    if (!__all(smax - m <= 8.0f)) {
      const float mnew = fmaxf(m, smax);
      const float corr = fexp2(m - mnew);
      lsum *= corr;
      #pragma unroll
      for (int dt = 0; dt < 4; ++dt) oacc[dt] *= corr;
      m = mnew;
    }

    float ssum = 0.f;
    #pragma unroll
    for (int kt = 0; kt < 4; ++kt) {
      float p0 = fexp2(sacc[kt][0] - m);
      float p1 = fexp2(sacc[kt][1] - m);
      float p2 = fexp2(sacc[kt][2] - m);
      float p3 = fexp2(sacc[kt][3] - m);
      ssum += (p0 + p1) + (p2 + p3);
      unsigned pk01, pk23;
      asm("v_cvt_pk_bf16_f32 %0, %1, %2" : "=v"(pk01) : "v"(p0), "v"(p1));
      asm("v_cvt_pk_bf16_f32 %0, %1, %2" : "=v"(pk23) : "v"(p2), "v"(p3));
      uint2 pv; pv.x = pk01; pv.y = pk23;
      *reinterpret_cast<uint2*>(
          &Pt[wid][c * 72 + ((kt ^ csw) << 4) + G * 4]) = pv;
    }
    ssum += __shfl_xor(ssum, 16);
    ssum += __shfl_xor(ssum, 32);
    lsum += ssum;

    __builtin_amdgcn_s_setprio(1);
    #pragma unroll
    for (int kf = 0; kf < 2; ++kf) {
      // P k-chunk = 2kf + (G>>1), offset (G&1)*8; chunk XOR-swizzled by csw
      short8v pf = *reinterpret_cast<const short8v*>(
          &Pt[wid][c * 72 + (((2 * kf + (G >> 1)) ^ csw) << 4) + (G & 1) * 8]);
      #pragma unroll
      for (int dt = 0; dt < 4; ++dt) {
        const int d = dt * 16 + c;
        short8v vf = *reinterpret_cast<const short8v*>(
            Vt + d * 64 + (((kf * 4 + G) ^ (d & 7)) << 3));
        oacc[dt] = __builtin_amdgcn_mfma_f32_16x16x32_bf16(vf, pf, oacc[dt], 0, 0, 0);
      }
    }
    __builtin_amdgcn_s_setprio(0);
    __syncthreads();
  }

  const int q = wid * 16 + c;
  const size_t pb = ((size_t)((bh * 13 + qb) * NSEG + ks)) * 64 + q;
  u16* op = OpartB + pb * 64;
  #pragma unroll
  for (int dt = 0; dt < 4; ++dt) {
    short4v o;
    o[0] = (short)f2bf(oacc[dt][0]); o[1] = (short)f2bf(oacc[dt][1]);
    o[2] = (short)f2bf(oacc[dt][2]); o[3] = (short)f2bf(oacc[dt][3]);
    *reinterpret_cast<short4v*>(op + dt * 16 + G * 4) = o;
  }
  if (G == 0) {
    MLpart[pb * 2]     = m;     // log2-domain running max
    MLpart[pb * 2 + 1] = lsum;
  }
}

// ---------------------------------------------------------------------------
// 4-way split-K combine (log2-domain m): O = sum Oi*ci / sum li*ci, bf16 out.
// ---------------------------------------------------------------------------
__global__ __launch_bounds__(256) void attn_combine(
    const u16* __restrict__ OpartB, const float* __restrict__ MLpart,
    const int* __restrict__ tix, u16* __restrict__ O1b)
{
  const int bq = blockIdx.x;
  const int bh = bq / 13, qb = bq % 13;
  const int tid = threadIdx.x;
  const int q = tid >> 2, dq = (tid & 3) * 16;
  const int rglob = qb * 64 + q;
  if (rglob >= TOPU) return;
  const int rowidx = tix[bh * TOPU + rglob];

  size_t p[NSEG];
  float mi[NSEG], li[NSEG];
  #pragma unroll
  for (int i = 0; i < NSEG; ++i) {
    p[i] = ((size_t)bq * NSEG + i) * 64 + q;
    mi[i] = MLpart[p[i] * 2];
    li[i] = MLpart[p[i] * 2 + 1];
  }
  float mx = fmaxf(fmaxf(mi[0], mi[1]), fmaxf(mi[2], mi[3]));
  float ci[NSEG], lsum = 0.f;
  #pragma unroll
  for (int i = 0; i < NSEG; ++i) { ci[i] = fexp2(mi[i] - mx); lsum += li[i] * ci[i]; }
  const float linv = 1.0f / lsum;

  float acc[16];
  #pragma unroll
  for (int j = 0; j < 16; ++j) acc[j] = 0.f;
  #pragma unroll
  for (int i = 0; i < NSEG; ++i) {
    const u16* src = OpartB + p[i] * 64 + dq;
    #pragma unroll
    for (int j = 0; j < 16; ++j) acc[j] += bf2f(src[j]) * ci[i];
  }

  const int b = bh >> 4, h = bh & 15;
  u16* dst = O1b + (size_t)(b * LSEQ + rowidx) * DM + h * HD + dq;
  #pragma unroll
  for (int j0 = 0; j0 < 16; j0 += 4) {
    short4v o;
    #pragma unroll
    for (int j = 0; j < 4; ++j) o[j] = (short)f2bf(acc[j0 + j] * linv);
    *reinterpret_cast<short4v*>(dst + j0) = o;
  }
}

// ---------------------------------------------------------------------------
extern "C" void kernel_launch(void* const* d_in, const int* in_sizes, int n_in,
                              void* d_out, int out_size, void* d_ws, size_t ws_size,
                              hipStream_t stream) {
  const float* x  = (const float*)d_in[0];
  const float* Wq = (const float*)d_in[1];
  const float* bq = (const float*)d_in[2];
  const float* Wk = (const float*)d_in[3];
  const float* bk = (const float*)d_in[4];
  const float* Wv = (const float*)d_in[5];
  const float* bv = (const float*)d_in[6];
  const float* Wo = (const float*)d_in[7];
  const float* bo = (const float*)d_in[8];
  float* out = (float*)d_out;

  char* w = (char*)d_ws;
  u16* xb   = (u16*)w;  w += (size_t)MROWS * DM * 2;           // 16 MB -> OpartB/ML
  u16* Qbb  = (u16*)w;  w += (size_t)BHT * LSEQ * HD * 2;      // 16 MB
  u16* Kb   = (u16*)w;  w += (size_t)BHT * LSEQ * HD * 2;      // 16 MB
  u16* VgT  = (u16*)w;  w += (size_t)BHT * HD * LSEQ * 2;      // 16 MB
  u16* O1b  = (u16*)w;  w += (size_t)MROWS * DM * 2;           // 16 MB
  u16* Wqb  = (u16*)w;  w += (size_t)DM * DM * 2;              // 2 MB
  u16* Wkb  = (u16*)w;  w += (size_t)DM * DM * 2;
  u16* Wvb  = (u16*)w;  w += (size_t)DM * DM * 2;
  u16* Wob  = (u16*)w;  w += (size_t)DM * DM * 2;
  float* norms = (float*)w; w += (size_t)BHT * LSEQ * 4;       // 512 KB
  int* tix  = (int*)w;  w += (size_t)BHT * TOPU * 4;           // 105 KB
  u64* ukeys = (u64*)w; w += (size_t)BHT * UCAP * 8;           // 256 KB
  int* Dcnt = (int*)w;  w += 128;
  int* Ucnt = (int*)w;  w += 128;

  // attn partials alias xb (dead after gemm_proj): 13.6 + 0.85 MB <= 16 MB
  u16*   OpartB = xb;
  const int NPB = BHT * 13 * NSEG * 64;
  float* MLpart = (float*)(OpartB + (size_t)NPB * 64);

  prep_all<<<6144, 256, 0, stream>>>(x, Wq, Wk, Wv, Wo, xb, Wqb, Wkb, Wvb, Wob);

  gemm_proj<<<dim3(64, 24), 256, 0, stream>>>(
      xb, Wqb, Wkb, Wvb, bq, bk, bv, Qbb, norms, Kb, VgT);

  selectA<<<BHT, 1024, 0, stream>>>(norms, tix, ukeys, Dcnt, Ucnt);
  recompute_norms<<<dim3(BHT, UCAP), 256, 0, stream>>>(x, Wq, bq, ukeys, Ucnt);
  selectB<<<BHT, 1024, 0, stream>>>(ukeys, Dcnt, Ucnt, tix);

  hipMemsetAsync(O1b, 0, (size_t)MROWS * DM * 2, stream);

  attn_mfma<<<BHT * 13 * NSEG, 256, 0, stream>>>(Qbb, Kb, VgT, tix, OpartB, MLpart);
  attn_combine<<<BHT * 13, 256, 0, stream>>>(OpartB, MLpart, tix, O1b);

  gemm_out<<<dim3(MROWS / 128, DM / 128), 256, 0, stream>>>(O1b, Wob, bo, out);
}